// Round 8
// baseline (1841.422 us; speedup 1.0000x reference)
//
#include <hip/hip_runtime.h>
#include <hip/hip_bf16.h>

#define LRELU_SLOPE 0.2f
#define GRID 1024
#define WTOT 108544  // 65536 + 32768 + 8192 + 2048

typedef __attribute__((ext_vector_type(8))) short short8;
typedef __attribute__((ext_vector_type(4))) float f32x4;

__device__ __forceinline__ unsigned short bf16r(float f) {
    unsigned int u = __builtin_bit_cast(unsigned int, f);
    u += 0x7fffu + ((u >> 16) & 1u);   // RNE
    return (unsigned short)(u >> 16);
}
__device__ __forceinline__ float bf2f(unsigned short u) {
    return __builtin_bit_cast(float, (unsigned int)u << 16);
}

// async global->LDS 16B DMA
#define GLD16(g, l)                                                            \
    __builtin_amdgcn_global_load_lds(                                          \
        (const __attribute__((address_space(1))) void*)(g),                    \
        (__attribute__((address_space(3))) void*)(l), 16, 0, 0)

#define QB(v, k) __builtin_amdgcn_ds_swizzle((v), 0x8000 | ((k) * 0x55))

struct MArgs {
    const float* x; const int* ei;
    const float *W0, *W1, *W2, *W3;
    const float *as0, *as1, *as2, *as3;
    const float *ad0, *ad1, *ad2, *ad3;
    const float *b0, *b1, *b2, *b3;
    unsigned short *WT0, *WT1, *WT2, *WT3;
    int *bar, *cnt, *slot, *offsR, *offs, *adj, *csum;
    float *sbuf, *dbuf;
    unsigned short *Xb, *Yb;
    float* dout;
    int N, E, XC;
};

// ---- hand-rolled grid barrier: per-phase monotonic counters (zeroed each run
// by the host memset). Residency guaranteed: launch_bounds(256,4) + 32KB LDS
// -> exactly 4 blocks/CU x 256 CU = GRID blocks co-resident, so the spin
// cannot deadlock. Release add + acquire spin + threadfence = the same
// device-scope fence machinery r16's last-done-block scan proved on this HW
// (cross-XCD L2 wb/inv via agent-scope fence).
__device__ __forceinline__ void gbar(int* bar, int ph) {
    __syncthreads();
    if (threadIdx.x == 0) {
        __threadfence();
        __hip_atomic_fetch_add(&bar[ph], 1, __ATOMIC_RELEASE, __HIP_MEMORY_SCOPE_AGENT);
        while (__hip_atomic_load(&bar[ph], __ATOMIC_ACQUIRE, __HIP_MEMORY_SCOPE_AGENT) < GRID)
            __builtin_amdgcn_s_sleep(2);
        __threadfence();
    }
    __syncthreads();
}

// ---------------- mgemm phase (r16 K-split DMA structure, persistent) ----------------

template<int BN, int KT, int GX>
__device__ void mgemm_phase(const unsigned short* __restrict__ Ab,
                            const unsigned short* __restrict__ WT,
                            unsigned short* __restrict__ Cb,
                            const float* __restrict__ a_src, const float* __restrict__ a_dst,
                            float* __restrict__ sbuf, float* __restrict__ dbuf,
                            int M, int Nc, int H, int RB, int RBp,
                            unsigned short* LB) {
    constexpr int KH = (KT == 256) ? 128 : KT;
    constexpr int NR = KT / KH;
    constexpr int KITER = KH / 32;
    constexpr int NBF = BN / 16;
    constexpr int CPR = BN / 32;
    constexpr int SP  = BN + 8;
    constexpr int ASH = 64 * KH;
    constexpr int CHR = KH / 8;
    constexpr int SHC = (KH == 128) ? 4 : 3;
    constexpr int AIT = CHR / 4;
    constexpr int BIT = BN * CHR / 256;

    int t = threadIdx.x;
    int wv = t >> 6, l = t & 63;
    int row_in = l & 15, quad = l >> 4;
    char* LBb = (char*)LB;
    const char* Agb = (const char*)Ab;
    const char* WTb = (const char*)WT;
    int arow = wv * 16 + row_in;

    for (int id = blockIdx.x; id < GX * RBp; id += GRID) {
        __syncthreads();   // protect LB reuse from previous tile's epilogue reads
        int xcd = id & 7;
        int q  = id >> 3;
        int ct = q % GX;
        int rb = (q / GX) * 8 + xcd;
        if (rb >= RB) continue;
        int bm = rb * 64, bn = ct * BN;

        f32x4 acc[NBF];
#pragma unroll
        for (int j = 0; j < NBF; ++j) acc[j] = (f32x4){0.f, 0.f, 0.f, 0.f};

#pragma unroll
        for (int r = 0; r < NR; ++r) {
            if (r > 0) __syncthreads();
            // stage A half-tile via DMA (linear LDS dest, pre-swizzled source)
#pragma unroll
            for (int i = 0; i < AIT; ++i) {
                int c = i * 256 + t;
                int row = c >> SHC;
                int ci  = c & (CHR - 1);
                int cis = ci ^ (row & 7);
                int grow = bm + row; if (grow >= M) grow = M - 1;
                long gb = (long)grow * (KT * 2) + r * (KH * 2) + cis * 16;
                GLD16(Agb + gb, LBb + (i * 256 + wv * 64) * 16);
            }
            // stage B half-tile via DMA
#pragma unroll
            for (int i = 0; i < BIT; ++i) {
                int c = i * 256 + t;
                int col = c >> SHC;
                int ci  = c & (CHR - 1);
                int cis = ci ^ (col & 7);
                long gb = (long)(bn + col) * (KT * 2) + r * (KH * 2) + cis * 16;
                GLD16(WTb + gb, LBb + ASH * 2 + (i * 256 + wv * 64) * 16);
            }
            asm volatile("s_waitcnt vmcnt(0)" ::: "memory");
            __syncthreads();

            // K loop: pure LDS -> MFMA, swizzled b128 reads
#pragma unroll
            for (int ki = 0; ki < KITER; ++ki) {
                int aoff = (arow * (KH * 2) + ki * 64 + quad * 16) ^ ((arow & 7) << 4);
                short8 av = *(const short8*)(LBb + aoff);
#pragma unroll
                for (int f = 0; f < NBF; ++f) {
                    int bcol = f * 16 + row_in;
                    int boff = ASH * 2 + ((bcol * (KH * 2) + ki * 64 + quad * 16) ^ ((bcol & 7) << 4));
                    short8 bv = *(const short8*)(LBb + boff);
                    acc[f] = __builtin_amdgcn_mfma_f32_16x16x32_bf16(av, bv, acc[f], 0, 0, 0);
                }
            }
        }
        __syncthreads();   // before LDS reuse for epilogue

        // epilogue: LDS repack (bf16) -> coalesced stores + fused s/d
#pragma unroll
        for (int r = 0; r < 4; ++r)
#pragma unroll
            for (int f = 0; f < NBF; ++f)
                LB[(wv * 16 + quad * 4 + r) * SP + f * 16 + row_in] = bf16r(acc[f][r]);
        __syncthreads();

        int rr = t / CPR, cc = t % CPR;
        if (rr < 64) {
            int grow = bm + rr;
            int colb = bn + cc * 32;
            if (grow < M && colb < Nc) {
                const unsigned short* ep = &LB[rr * SP + cc * 32];
                short8 v0 = *(const short8*)(ep);
                short8 v1 = *(const short8*)(ep + 8);
                short8 v2 = *(const short8*)(ep + 16);
                short8 v3 = *(const short8*)(ep + 24);
                unsigned short* cp = &Cb[(long)grow * Nc + colb];
                *(short8*)(cp)      = v0;
                *(short8*)(cp + 8)  = v1;
                *(short8*)(cp + 16) = v2;
                *(short8*)(cp + 24) = v3;
                int hd = colb >> 5;
                const float* ap = a_src + hd * 32;
                const float* dp = a_dst + hd * 32;
                float ss = 0.f, dd = 0.f;
#pragma unroll
                for (int u = 0; u < 8; ++u) {
                    float va = bf2f((unsigned short)v0[u]); ss += va * ap[u];      dd += va * dp[u];
                    float vb = bf2f((unsigned short)v1[u]); ss += vb * ap[8 + u];  dd += vb * dp[8 + u];
                    float vc = bf2f((unsigned short)v2[u]); ss += vc * ap[16 + u]; dd += vc * dp[16 + u];
                    float vd = bf2f((unsigned short)v3[u]); ss += vd * ap[24 + u]; dd += vd * dp[24 + u];
                }
                sbuf[(long)grow * H + hd] = ss;
                dbuf[(long)grow * H + hd] = dd;
            }
        }
    }
}

// ---------------- aggf phase (r13 4-wide quad-coop, persistent) ----------------

template<int ACT>
__device__ void aggf_phase(const unsigned short* __restrict__ h, const float* __restrict__ s,
                           const float* __restrict__ dsc, const int* __restrict__ offs,
                           const int* __restrict__ adj, const float* __restrict__ bias,
                           unsigned short* __restrict__ out16, float* __restrict__ out32,
                           int N, int H) {
    const int C8 = 4;
    int HC8 = H * C8;
    long total = (long)N * HC8;
    int HC = HC8 * 8;
    for (long tid = (long)blockIdx.x * 256 + threadIdx.x; tid < total; tid += (long)GRID * 256) {
        int c8 = (int)(tid % C8);
        int hh = (int)((tid / C8) % H);
        int n  = (int)(tid / HC8);
        int beg = offs[n], end = offs[n + 1];
        float dn = dsc[n * H + hh];
        int coff = hh * 32 + c8 * 8;
        const unsigned short* hb = h + coff;

        float denom = 0.f;
        float acc[8];
#pragma unroll
        for (int u = 0; u < 8; ++u) acc[u] = 0.f;

        for (int j = beg; j < end; j += 4) {
            int my = j + c8;
            int idx = my < end ? my : end - 1;
            int sn = adj[idx];
            float e = s[sn * H + hh] + dn;
            e = e > 0.f ? e : LRELU_SLOPE * e;
            float w = __expf(fminf(e, 80.f));
            if (my >= end) w = 0.f;
            int wi = __builtin_bit_cast(int, w);
            int sn0 = QB(sn, 0);
            int sn1 = QB(sn, 1);
            int sn2 = QB(sn, 2);
            int sn3 = QB(sn, 3);
            float w0 = __builtin_bit_cast(float, QB(wi, 0));
            float w1 = __builtin_bit_cast(float, QB(wi, 1));
            float w2 = __builtin_bit_cast(float, QB(wi, 2));
            float w3 = __builtin_bit_cast(float, QB(wi, 3));
            short8 h0 = *(const short8*)(hb + (size_t)sn0 * HC);
            short8 h1 = *(const short8*)(hb + (size_t)sn1 * HC);
            short8 h2 = *(const short8*)(hb + (size_t)sn2 * HC);
            short8 h3 = *(const short8*)(hb + (size_t)sn3 * HC);
            denom += (w0 + w1) + (w2 + w3);
#pragma unroll
            for (int u = 0; u < 8; ++u) {
                float a01 = w0 * bf2f((unsigned short)h0[u]) + w1 * bf2f((unsigned short)h1[u]);
                float a23 = w2 * bf2f((unsigned short)h2[u]) + w3 * bf2f((unsigned short)h3[u]);
                acc[u] += a01 + a23;
            }
        }

        float inv = 1.0f / denom;
        float o[8];
#pragma unroll
        for (int u = 0; u < 8; ++u) o[u] = acc[u] * inv + bias[coff + u];

        if (ACT == 1) {
            short8 pk;
#pragma unroll
            for (int u = 0; u < 8; ++u) {
                float v = o[u] > 0.f ? o[u] : (__expf(o[u]) - 1.f);
                pk[u] = (short)bf16r(v);
            }
            *(short8*)(out16 + tid * 8) = pk;
        } else {
            float m = o[0];
#pragma unroll
            for (int u = 1; u < 8; ++u) m = fmaxf(m, o[u]);
            m = fmaxf(m, __shfl_xor(m, 1));
            m = fmaxf(m, __shfl_xor(m, 2));
            float ssum = 0.f;
#pragma unroll
            for (int u = 0; u < 8; ++u) ssum += __expf(o[u] - m);
            ssum += __shfl_xor(ssum, 1);
            ssum += __shfl_xor(ssum, 2);
            float lse = m + __logf(ssum);
            float4 lo = {o[0] - lse, o[1] - lse, o[2] - lse, o[3] - lse};
            float4 hi = {o[4] - lse, o[5] - lse, o[6] - lse, o[7] - lse};
            *(float4*)(out32 + tid * 8)     = lo;
            *(float4*)(out32 + tid * 8 + 4) = hi;
        }
    }
}

// ---------------- mega-kernel: whole model, ONE plain launch ----------------
// r18: r17's cooperative launch never executed (dur NaN, output all-zero ->
// hipLaunchCooperativeKernel incompatible with the harness's graph capture).
// Same phase plan, plain <<<1024,256>>> + hand-rolled per-phase barrier.
// No early returns anywhere: every block reaches every gbar.

__global__ __launch_bounds__(256, 4) void k_mega(MArgs a) {
    __shared__ __align__(16) unsigned short LB[16384];   // 32 KB
    int t = threadIdx.x;
    int gtid = blockIdx.x * 256 + t;
    const int GT = GRID * 256;
    const int NC = (a.N + 255) >> 8;
    const int RB = (a.N + 63) / 64;
    const int RBp = ((RB + 7) / 8) * 8;
    int* LBi = (int*)LB;

    // ---- PhA: x->bf16 + W->WT transpose + edge count/slot (all independent) ----
    for (int i = gtid; i < a.XC; i += GT) {
        const float4* xp = (const float4*)a.x + (long)i * 2;
        float4 va = xp[0], vb = xp[1];
        short8 pk;
        pk[0] = (short)bf16r(va.x); pk[1] = (short)bf16r(va.y);
        pk[2] = (short)bf16r(va.z); pk[3] = (short)bf16r(va.w);
        pk[4] = (short)bf16r(vb.x); pk[5] = (short)bf16r(vb.y);
        pk[6] = (short)bf16r(vb.z); pk[7] = (short)bf16r(vb.w);
        *(short8*)(a.Xb + (long)i * 8) = pk;
    }
    for (int i0 = gtid; i0 < WTOT; i0 += GT) {
        int id = i0;
        const float* W; unsigned short* T; int K, Nc;
        if (id < 65536)       { W = a.W0; T = a.WT0; K = 256; Nc = 256; }
        else if (id < 98304)  { id -= 65536;  W = a.W1; T = a.WT1; K = 256; Nc = 128; }
        else if (id < 106496) { id -= 98304;  W = a.W2; T = a.WT2; K = 128; Nc = 64; }
        else                  { id -= 106496; W = a.W3; T = a.WT3; K = 64;  Nc = 32; }
        int n = id / K, k = id % K;
        T[id] = bf16r(W[(long)k * Nc + n]);
    }
    for (int e = gtid; e < a.E; e += GT) {
        int dst = a.ei[a.E + e];
        a.slot[e] = atomicAdd(&a.cnt[dst], 1);
    }
    gbar(a.bar, 0);

    // ---- PhB: per-chunk scans (cnt ready) + mgemm L0 (Xb/WT0 ready) ----
    for (int c = blockIdx.x; c < NC; c += GRID) {
        __syncthreads();
        int n = (c << 8) + t;
        int v = (n < a.N) ? a.cnt[n] + 1 : 0;    // +1: self-loop at segment head
        LBi[t] = v;
        __syncthreads();
        for (int o = 1; o < 256; o <<= 1) {
            int xv = (t >= o) ? LBi[t - o] : 0;
            __syncthreads();
            LBi[t] += xv;
            __syncthreads();
        }
        int incl = LBi[t];
        if (n < a.N) a.offsR[n] = incl - v;      // exclusive within chunk
        if (t == 255) a.csum[c] = incl;
    }
    mgemm_phase<64, 256, 4>(a.Xb, a.WT0, a.Yb, a.as0, a.ad0, a.sbuf, a.dbuf,
                            a.N, 256, 8, RB, RBp, LB);
    gbar(a.bar, 1);

    // ---- PhC: redundant top-scan (every block, LDS) + finalize + scatter ----
    {
        int v = (t < NC) ? a.csum[t] : 0;
        LBi[t] = v;
        __syncthreads();
        for (int o = 1; o < 256; o <<= 1) {
            int xv = (t >= o) ? LBi[t - o] : 0;
            __syncthreads();
            LBi[t] += xv;
            __syncthreads();
        }
        int incl = LBi[t];
        if (blockIdx.x == 0 && t == NC - 1) a.offs[a.N] = incl;
        __syncthreads();
        LBi[t] = incl - v;          // exclusive chunk prefix, stays LDS-resident
        __syncthreads();
        for (int c = blockIdx.x; c < NC; c += GRID) {
            int n = (c << 8) + t;
            if (n < a.N) {
                int vo = a.offsR[n] + LBi[c];
                a.offs[n] = vo;
                a.adj[vo] = n;          // self-loop at segment head
            }
        }
        for (int e = gtid; e < a.E; e += GT) {
            int dst = a.ei[a.E + e];
            a.adj[a.offsR[dst] + LBi[dst >> 8] + 1 + a.slot[e]] = a.ei[e];   // no atomics
        }
    }
    gbar(a.bar, 2);

    // ---- layers (L0 mgemm already done in PhB) ----
    aggf_phase<1>(a.Yb, a.sbuf, a.dbuf, a.offs, a.adj, a.b0, a.Xb, nullptr, a.N, 8);
    gbar(a.bar, 3);
    mgemm_phase<64, 256, 2>(a.Xb, a.WT1, a.Yb, a.as1, a.ad1, a.sbuf, a.dbuf,
                            a.N, 128, 4, RB, RBp, LB);
    gbar(a.bar, 4);
    aggf_phase<1>(a.Yb, a.sbuf, a.dbuf, a.offs, a.adj, a.b1, a.Xb, nullptr, a.N, 4);
    gbar(a.bar, 5);
    mgemm_phase<64, 128, 1>(a.Xb, a.WT2, a.Yb, a.as2, a.ad2, a.sbuf, a.dbuf,
                            a.N, 64, 2, RB, RBp, LB);
    gbar(a.bar, 6);
    aggf_phase<1>(a.Yb, a.sbuf, a.dbuf, a.offs, a.adj, a.b2, a.Xb, nullptr, a.N, 2);
    gbar(a.bar, 7);
    mgemm_phase<32, 64, 1>(a.Xb, a.WT3, a.Yb, a.as3, a.ad3, a.sbuf, a.dbuf,
                            a.N, 32, 1, RB, RBp, LB);
    gbar(a.bar, 8);
    aggf_phase<0>(a.Yb, a.sbuf, a.dbuf, a.offs, a.adj, a.b3, nullptr, a.dout, a.N, 1);
}

// ---------------- host ----------------

static inline size_t align_up(size_t x) { return (x + 255) & ~(size_t)255; }

extern "C" void kernel_launch(void* const* d_in, const int* in_sizes, int n_in,
                              void* d_out, int out_size, void* d_ws, size_t ws_size,
                              hipStream_t stream) {
    const int N = in_sizes[0] / 256;   // 50000
    const int E = in_sizes[1] / 2;     // 400000
    const int ET = E + N;
    const int XC = N * 32;

    size_t off = 0;
    char* ws = (char*)d_ws;
    auto take = [&](size_t bytes) { char* p = ws + off; off += align_up(bytes); return p; };
    int*   barcnt = (int*)take((size_t)(16 + N) * 4);   // bar[16] + cnt[N], one memset
    int*   offs  = (int*)take((size_t)(N + 1) * 4);
    int*   offsR = (int*)take((size_t)(N + 1) * 4);
    int*   slot  = (int*)take((size_t)E * 4);
    int*   adj   = (int*)take((size_t)ET * 4);
    int*   csum  = (int*)take((size_t)256 * 4);
    float* sbuf  = (float*)take((size_t)N * 8 * 4);
    float* dbuf  = (float*)take((size_t)N * 8 * 4);
    unsigned short* Xb = (unsigned short*)take((size_t)N * 256 * 2);
    unsigned short* Yb = (unsigned short*)take((size_t)N * 256 * 2);
    unsigned short* WT0 = (unsigned short*)take((size_t)256 * 256 * 2);
    unsigned short* WT1 = (unsigned short*)take((size_t)256 * 128 * 2);
    unsigned short* WT2 = (unsigned short*)take((size_t)128 * 64 * 2);
    unsigned short* WT3 = (unsigned short*)take((size_t)64 * 32 * 2);
    (void)ws_size;

    MArgs ha;
    ha.x = (const float*)d_in[0];
    ha.ei = (const int*)d_in[1];
    ha.W0 = (const float*)d_in[2];  ha.as0 = (const float*)d_in[3];
    ha.ad0 = (const float*)d_in[4]; ha.b0 = (const float*)d_in[5];
    ha.W1 = (const float*)d_in[6];  ha.as1 = (const float*)d_in[7];
    ha.ad1 = (const float*)d_in[8]; ha.b1 = (const float*)d_in[9];
    ha.W2 = (const float*)d_in[10]; ha.as2 = (const float*)d_in[11];
    ha.ad2 = (const float*)d_in[12]; ha.b2 = (const float*)d_in[13];
    ha.W3 = (const float*)d_in[14]; ha.as3 = (const float*)d_in[15];
    ha.ad3 = (const float*)d_in[16]; ha.b3 = (const float*)d_in[17];
    ha.WT0 = WT0; ha.WT1 = WT1; ha.WT2 = WT2; ha.WT3 = WT3;
    ha.bar = barcnt; ha.cnt = barcnt + 16;
    ha.slot = slot; ha.offsR = offsR; ha.offs = offs;
    ha.adj = adj; ha.csum = csum;
    ha.sbuf = sbuf; ha.dbuf = dbuf; ha.Xb = Xb; ha.Yb = Yb;
    ha.dout = (float*)d_out;
    ha.N = N; ha.E = E; ha.XC = XC;

    // zero barrier counters + cnt (one memset; re-runs on every graph replay)
    hipMemsetAsync(barcnt, 0, (size_t)(16 + N) * 4, stream);
    k_mega<<<GRID, 256, 0, stream>>>(ha);
}

// Round 9
// 1353.222 us; speedup vs baseline: 1.3608x; 1.3608x over previous
//
#include <hip/hip_runtime.h>
#include <hip/hip_bf16.h>

#define LRELU_SLOPE 0.2f
#define GRID 1024
#define WTOT 108544  // 65536 + 32768 + 8192 + 2048

typedef __attribute__((ext_vector_type(8))) short short8;
typedef __attribute__((ext_vector_type(4))) float f32x4;

__device__ __forceinline__ unsigned short bf16r(float f) {
    unsigned int u = __builtin_bit_cast(unsigned int, f);
    u += 0x7fffu + ((u >> 16) & 1u);   // RNE
    return (unsigned short)(u >> 16);
}
__device__ __forceinline__ float bf2f(unsigned short u) {
    return __builtin_bit_cast(float, (unsigned int)u << 16);
}

// async global->LDS 16B DMA
#define GLD16(g, l)                                                            \
    __builtin_amdgcn_global_load_lds(                                          \
        (const __attribute__((address_space(1))) void*)(g),                    \
        (__attribute__((address_space(3))) void*)(l), 16, 0, 0)

#define QB(v, k) __builtin_amdgcn_ds_swizzle((v), 0x8000 | ((k) * 0x55))

struct MArgs {
    const float* x; const int* ei;
    const float *W0, *W1, *W2, *W3;
    const float *as0, *as1, *as2, *as3;
    const float *ad0, *ad1, *ad2, *ad3;
    const float *b0, *b1, *b2, *b3;
    unsigned short *WT0, *WT1, *WT2, *WT3;
    int *bar, *cnt, *slot, *offsR, *offs, *adj, *csum;
    float *sbuf, *dbuf;
    unsigned short *Xb, *Yb;
    float* dout;
    int N, E, XC;
};

// ---- grid barrier, r19: RELAXED poll + single fences (RCCL pattern).
// r18's acquire-load spin emitted cache-maintenance (L2 inv) every ~128 cycles
// per block -> invalidate storm during phase-end skew -> 6x slowdown with
// VALUBusy 2.6% and normal FETCH (L3 absorbed the re-fetches). A relaxed
// agent-scope atomic load still reads the coherence point (fresh value) but
// carries no invalidate; one threadfence each side provides release/acquire.
__device__ __forceinline__ void gbar(int* bar, int ph) {
    __syncthreads();
    if (threadIdx.x == 0) {
        __threadfence();                       // release: publish phase writes
        atomicAdd(&bar[ph], 1);                // device-scope RMW (coherence point)
        while (__hip_atomic_load(&bar[ph], __ATOMIC_RELAXED,
                                 __HIP_MEMORY_SCOPE_AGENT) < GRID)
            __builtin_amdgcn_s_sleep(8);       // ~512-cycle backoff, no cache ops
        __threadfence();                       // acquire: see others' writes
    }
    __syncthreads();
}

// ---------------- mgemm phase (r16 K-split DMA structure, persistent) ----------------

template<int BN, int KT, int GX>
__device__ void mgemm_phase(const unsigned short* __restrict__ Ab,
                            const unsigned short* __restrict__ WT,
                            unsigned short* __restrict__ Cb,
                            const float* __restrict__ a_src, const float* __restrict__ a_dst,
                            float* __restrict__ sbuf, float* __restrict__ dbuf,
                            int M, int Nc, int H, int RB, int RBp,
                            unsigned short* LB) {
    constexpr int KH = (KT == 256) ? 128 : KT;
    constexpr int NR = KT / KH;
    constexpr int KITER = KH / 32;
    constexpr int NBF = BN / 16;
    constexpr int CPR = BN / 32;
    constexpr int SP  = BN + 8;
    constexpr int ASH = 64 * KH;
    constexpr int CHR = KH / 8;
    constexpr int SHC = (KH == 128) ? 4 : 3;
    constexpr int AIT = CHR / 4;
    constexpr int BIT = BN * CHR / 256;

    int t = threadIdx.x;
    int wv = t >> 6, l = t & 63;
    int row_in = l & 15, quad = l >> 4;
    char* LBb = (char*)LB;
    const char* Agb = (const char*)Ab;
    const char* WTb = (const char*)WT;
    int arow = wv * 16 + row_in;

    for (int id = blockIdx.x; id < GX * RBp; id += GRID) {
        __syncthreads();   // protect LB reuse from previous tile's epilogue reads
        int xcd = id & 7;
        int q  = id >> 3;
        int ct = q % GX;
        int rb = (q / GX) * 8 + xcd;
        if (rb >= RB) continue;
        int bm = rb * 64, bn = ct * BN;

        f32x4 acc[NBF];
#pragma unroll
        for (int j = 0; j < NBF; ++j) acc[j] = (f32x4){0.f, 0.f, 0.f, 0.f};

#pragma unroll
        for (int r = 0; r < NR; ++r) {
            if (r > 0) __syncthreads();
            // stage A half-tile via DMA (linear LDS dest, pre-swizzled source)
#pragma unroll
            for (int i = 0; i < AIT; ++i) {
                int c = i * 256 + t;
                int row = c >> SHC;
                int ci  = c & (CHR - 1);
                int cis = ci ^ (row & 7);
                int grow = bm + row; if (grow >= M) grow = M - 1;
                long gb = (long)grow * (KT * 2) + r * (KH * 2) + cis * 16;
                GLD16(Agb + gb, LBb + (i * 256 + wv * 64) * 16);
            }
            // stage B half-tile via DMA
#pragma unroll
            for (int i = 0; i < BIT; ++i) {
                int c = i * 256 + t;
                int col = c >> SHC;
                int ci  = c & (CHR - 1);
                int cis = ci ^ (col & 7);
                long gb = (long)(bn + col) * (KT * 2) + r * (KH * 2) + cis * 16;
                GLD16(WTb + gb, LBb + ASH * 2 + (i * 256 + wv * 64) * 16);
            }
            asm volatile("s_waitcnt vmcnt(0)" ::: "memory");
            __syncthreads();

            // K loop: pure LDS -> MFMA, swizzled b128 reads
#pragma unroll
            for (int ki = 0; ki < KITER; ++ki) {
                int aoff = (arow * (KH * 2) + ki * 64 + quad * 16) ^ ((arow & 7) << 4);
                short8 av = *(const short8*)(LBb + aoff);
#pragma unroll
                for (int f = 0; f < NBF; ++f) {
                    int bcol = f * 16 + row_in;
                    int boff = ASH * 2 + ((bcol * (KH * 2) + ki * 64 + quad * 16) ^ ((bcol & 7) << 4));
                    short8 bv = *(const short8*)(LBb + boff);
                    acc[f] = __builtin_amdgcn_mfma_f32_16x16x32_bf16(av, bv, acc[f], 0, 0, 0);
                }
            }
        }
        __syncthreads();   // before LDS reuse for epilogue

        // epilogue: LDS repack (bf16) -> coalesced stores + fused s/d
#pragma unroll
        for (int r = 0; r < 4; ++r)
#pragma unroll
            for (int f = 0; f < NBF; ++f)
                LB[(wv * 16 + quad * 4 + r) * SP + f * 16 + row_in] = bf16r(acc[f][r]);
        __syncthreads();

        int rr = t / CPR, cc = t % CPR;
        if (rr < 64) {
            int grow = bm + rr;
            int colb = bn + cc * 32;
            if (grow < M && colb < Nc) {
                const unsigned short* ep = &LB[rr * SP + cc * 32];
                short8 v0 = *(const short8*)(ep);
                short8 v1 = *(const short8*)(ep + 8);
                short8 v2 = *(const short8*)(ep + 16);
                short8 v3 = *(const short8*)(ep + 24);
                unsigned short* cp = &Cb[(long)grow * Nc + colb];
                *(short8*)(cp)      = v0;
                *(short8*)(cp + 8)  = v1;
                *(short8*)(cp + 16) = v2;
                *(short8*)(cp + 24) = v3;
                int hd = colb >> 5;
                const float* ap = a_src + hd * 32;
                const float* dp = a_dst + hd * 32;
                float ss = 0.f, dd = 0.f;
#pragma unroll
                for (int u = 0; u < 8; ++u) {
                    float va = bf2f((unsigned short)v0[u]); ss += va * ap[u];      dd += va * dp[u];
                    float vb = bf2f((unsigned short)v1[u]); ss += vb * ap[8 + u];  dd += vb * dp[8 + u];
                    float vc = bf2f((unsigned short)v2[u]); ss += vc * ap[16 + u]; dd += vc * dp[16 + u];
                    float vd = bf2f((unsigned short)v3[u]); ss += vd * ap[24 + u]; dd += vd * dp[24 + u];
                }
                sbuf[(long)grow * H + hd] = ss;
                dbuf[(long)grow * H + hd] = dd;
            }
        }
    }
}

// ---------------- aggf phase (r13 4-wide quad-coop, persistent) ----------------

template<int ACT>
__device__ void aggf_phase(const unsigned short* __restrict__ h, const float* __restrict__ s,
                           const float* __restrict__ dsc, const int* __restrict__ offs,
                           const int* __restrict__ adj, const float* __restrict__ bias,
                           unsigned short* __restrict__ out16, float* __restrict__ out32,
                           int N, int H) {
    const int C8 = 4;
    int HC8 = H * C8;
    long total = (long)N * HC8;
    int HC = HC8 * 8;
    for (long tid = (long)blockIdx.x * 256 + threadIdx.x; tid < total; tid += (long)GRID * 256) {
        int c8 = (int)(tid % C8);
        int hh = (int)((tid / C8) % H);
        int n  = (int)(tid / HC8);
        int beg = offs[n], end = offs[n + 1];
        float dn = dsc[n * H + hh];
        int coff = hh * 32 + c8 * 8;
        const unsigned short* hb = h + coff;

        float denom = 0.f;
        float acc[8];
#pragma unroll
        for (int u = 0; u < 8; ++u) acc[u] = 0.f;

        for (int j = beg; j < end; j += 4) {
            int my = j + c8;
            int idx = my < end ? my : end - 1;
            int sn = adj[idx];
            float e = s[sn * H + hh] + dn;
            e = e > 0.f ? e : LRELU_SLOPE * e;
            float w = __expf(fminf(e, 80.f));
            if (my >= end) w = 0.f;
            int wi = __builtin_bit_cast(int, w);
            int sn0 = QB(sn, 0);
            int sn1 = QB(sn, 1);
            int sn2 = QB(sn, 2);
            int sn3 = QB(sn, 3);
            float w0 = __builtin_bit_cast(float, QB(wi, 0));
            float w1 = __builtin_bit_cast(float, QB(wi, 1));
            float w2 = __builtin_bit_cast(float, QB(wi, 2));
            float w3 = __builtin_bit_cast(float, QB(wi, 3));
            short8 h0 = *(const short8*)(hb + (size_t)sn0 * HC);
            short8 h1 = *(const short8*)(hb + (size_t)sn1 * HC);
            short8 h2 = *(const short8*)(hb + (size_t)sn2 * HC);
            short8 h3 = *(const short8*)(hb + (size_t)sn3 * HC);
            denom += (w0 + w1) + (w2 + w3);
#pragma unroll
            for (int u = 0; u < 8; ++u) {
                float a01 = w0 * bf2f((unsigned short)h0[u]) + w1 * bf2f((unsigned short)h1[u]);
                float a23 = w2 * bf2f((unsigned short)h2[u]) + w3 * bf2f((unsigned short)h3[u]);
                acc[u] += a01 + a23;
            }
        }

        float inv = 1.0f / denom;
        float o[8];
#pragma unroll
        for (int u = 0; u < 8; ++u) o[u] = acc[u] * inv + bias[coff + u];

        if (ACT == 1) {
            short8 pk;
#pragma unroll
            for (int u = 0; u < 8; ++u) {
                float v = o[u] > 0.f ? o[u] : (__expf(o[u]) - 1.f);
                pk[u] = (short)bf16r(v);
            }
            *(short8*)(out16 + tid * 8) = pk;
        } else {
            float m = o[0];
#pragma unroll
            for (int u = 1; u < 8; ++u) m = fmaxf(m, o[u]);
            m = fmaxf(m, __shfl_xor(m, 1));
            m = fmaxf(m, __shfl_xor(m, 2));
            float ssum = 0.f;
#pragma unroll
            for (int u = 0; u < 8; ++u) ssum += __expf(o[u] - m);
            ssum += __shfl_xor(ssum, 1);
            ssum += __shfl_xor(ssum, 2);
            float lse = m + __logf(ssum);
            float4 lo = {o[0] - lse, o[1] - lse, o[2] - lse, o[3] - lse};
            float4 hi = {o[4] - lse, o[5] - lse, o[6] - lse, o[7] - lse};
            *(float4*)(out32 + tid * 8)     = lo;
            *(float4*)(out32 + tid * 8 + 4) = hi;
        }
    }
}

// ---------------- mega-kernel: whole model, ONE plain launch ----------------
// r19 = r18 (correct, but 1771us from acquire-spin invalidate storm) with the
// relaxed-poll barrier. No early returns: every block reaches every gbar.

__global__ __launch_bounds__(256, 4) void k_mega(MArgs a) {
    __shared__ __align__(16) unsigned short LB[16384];   // 32 KB
    int t = threadIdx.x;
    int gtid = blockIdx.x * 256 + t;
    const int GT = GRID * 256;
    const int NC = (a.N + 255) >> 8;
    const int RB = (a.N + 63) / 64;
    const int RBp = ((RB + 7) / 8) * 8;
    int* LBi = (int*)LB;

    // ---- PhA: x->bf16 + W->WT transpose + edge count/slot (all independent) ----
    for (int i = gtid; i < a.XC; i += GT) {
        const float4* xp = (const float4*)a.x + (long)i * 2;
        float4 va = xp[0], vb = xp[1];
        short8 pk;
        pk[0] = (short)bf16r(va.x); pk[1] = (short)bf16r(va.y);
        pk[2] = (short)bf16r(va.z); pk[3] = (short)bf16r(va.w);
        pk[4] = (short)bf16r(vb.x); pk[5] = (short)bf16r(vb.y);
        pk[6] = (short)bf16r(vb.z); pk[7] = (short)bf16r(vb.w);
        *(short8*)(a.Xb + (long)i * 8) = pk;
    }
    for (int i0 = gtid; i0 < WTOT; i0 += GT) {
        int id = i0;
        const float* W; unsigned short* T; int K, Nc;
        if (id < 65536)       { W = a.W0; T = a.WT0; K = 256; Nc = 256; }
        else if (id < 98304)  { id -= 65536;  W = a.W1; T = a.WT1; K = 256; Nc = 128; }
        else if (id < 106496) { id -= 98304;  W = a.W2; T = a.WT2; K = 128; Nc = 64; }
        else                  { id -= 106496; W = a.W3; T = a.WT3; K = 64;  Nc = 32; }
        int n = id / K, k = id % K;
        T[id] = bf16r(W[(long)k * Nc + n]);
    }
    for (int e = gtid; e < a.E; e += GT) {
        int dst = a.ei[a.E + e];
        a.slot[e] = atomicAdd(&a.cnt[dst], 1);
    }
    gbar(a.bar, 0);

    // ---- PhB: per-chunk scans (cnt ready) + mgemm L0 (Xb/WT0 ready) ----
    for (int c = blockIdx.x; c < NC; c += GRID) {
        __syncthreads();
        int n = (c << 8) + t;
        int v = (n < a.N) ? a.cnt[n] + 1 : 0;    // +1: self-loop at segment head
        LBi[t] = v;
        __syncthreads();
        for (int o = 1; o < 256; o <<= 1) {
            int xv = (t >= o) ? LBi[t - o] : 0;
            __syncthreads();
            LBi[t] += xv;
            __syncthreads();
        }
        int incl = LBi[t];
        if (n < a.N) a.offsR[n] = incl - v;      // exclusive within chunk
        if (t == 255) a.csum[c] = incl;
    }
    mgemm_phase<64, 256, 4>(a.Xb, a.WT0, a.Yb, a.as0, a.ad0, a.sbuf, a.dbuf,
                            a.N, 256, 8, RB, RBp, LB);
    gbar(a.bar, 1);

    // ---- PhC: redundant top-scan (every block, LDS) + finalize + scatter ----
    {
        int v = (t < NC) ? a.csum[t] : 0;
        LBi[t] = v;
        __syncthreads();
        for (int o = 1; o < 256; o <<= 1) {
            int xv = (t >= o) ? LBi[t - o] : 0;
            __syncthreads();
            LBi[t] += xv;
            __syncthreads();
        }
        int incl = LBi[t];
        if (blockIdx.x == 0 && t == NC - 1) a.offs[a.N] = incl;
        __syncthreads();
        LBi[t] = incl - v;          // exclusive chunk prefix, stays LDS-resident
        __syncthreads();
        for (int c = blockIdx.x; c < NC; c += GRID) {
            int n = (c << 8) + t;
            if (n < a.N) {
                int vo = a.offsR[n] + LBi[c];
                a.offs[n] = vo;
                a.adj[vo] = n;          // self-loop at segment head
            }
        }
        for (int e = gtid; e < a.E; e += GT) {
            int dst = a.ei[a.E + e];
            a.adj[a.offsR[dst] + LBi[dst >> 8] + 1 + a.slot[e]] = a.ei[e];   // no atomics
        }
    }
    gbar(a.bar, 2);

    // ---- layers (L0 mgemm already done in PhB) ----
    aggf_phase<1>(a.Yb, a.sbuf, a.dbuf, a.offs, a.adj, a.b0, a.Xb, nullptr, a.N, 8);
    gbar(a.bar, 3);
    mgemm_phase<64, 256, 2>(a.Xb, a.WT1, a.Yb, a.as1, a.ad1, a.sbuf, a.dbuf,
                            a.N, 128, 4, RB, RBp, LB);
    gbar(a.bar, 4);
    aggf_phase<1>(a.Yb, a.sbuf, a.dbuf, a.offs, a.adj, a.b1, a.Xb, nullptr, a.N, 4);
    gbar(a.bar, 5);
    mgemm_phase<64, 128, 1>(a.Xb, a.WT2, a.Yb, a.as2, a.ad2, a.sbuf, a.dbuf,
                            a.N, 64, 2, RB, RBp, LB);
    gbar(a.bar, 6);
    aggf_phase<1>(a.Yb, a.sbuf, a.dbuf, a.offs, a.adj, a.b2, a.Xb, nullptr, a.N, 2);
    gbar(a.bar, 7);
    mgemm_phase<32, 64, 1>(a.Xb, a.WT3, a.Yb, a.as3, a.ad3, a.sbuf, a.dbuf,
                            a.N, 32, 1, RB, RBp, LB);
    gbar(a.bar, 8);
    aggf_phase<0>(a.Yb, a.sbuf, a.dbuf, a.offs, a.adj, a.b3, nullptr, a.dout, a.N, 1);
}

// ---------------- host ----------------

static inline size_t align_up(size_t x) { return (x + 255) & ~(size_t)255; }

extern "C" void kernel_launch(void* const* d_in, const int* in_sizes, int n_in,
                              void* d_out, int out_size, void* d_ws, size_t ws_size,
                              hipStream_t stream) {
    const int N = in_sizes[0] / 256;   // 50000
    const int E = in_sizes[1] / 2;     // 400000
    const int ET = E + N;
    const int XC = N * 32;

    size_t off = 0;
    char* ws = (char*)d_ws;
    auto take = [&](size_t bytes) { char* p = ws + off; off += align_up(bytes); return p; };
    int*   bar   = (int*)take((size_t)16 * 4);        // own 256B block (no false
    int*   cnt   = (int*)take((size_t)N * 4);         // sharing with cnt atomics)
    int*   offs  = (int*)take((size_t)(N + 1) * 4);
    int*   offsR = (int*)take((size_t)(N + 1) * 4);
    int*   slot  = (int*)take((size_t)E * 4);
    int*   adj   = (int*)take((size_t)ET * 4);
    int*   csum  = (int*)take((size_t)256 * 4);
    float* sbuf  = (float*)take((size_t)N * 8 * 4);
    float* dbuf  = (float*)take((size_t)N * 8 * 4);
    unsigned short* Xb = (unsigned short*)take((size_t)N * 256 * 2);
    unsigned short* Yb = (unsigned short*)take((size_t)N * 256 * 2);
    unsigned short* WT0 = (unsigned short*)take((size_t)256 * 256 * 2);
    unsigned short* WT1 = (unsigned short*)take((size_t)256 * 128 * 2);
    unsigned short* WT2 = (unsigned short*)take((size_t)128 * 64 * 2);
    unsigned short* WT3 = (unsigned short*)take((size_t)64 * 32 * 2);
    (void)ws_size;

    MArgs ha;
    ha.x = (const float*)d_in[0];
    ha.ei = (const int*)d_in[1];
    ha.W0 = (const float*)d_in[2];  ha.as0 = (const float*)d_in[3];
    ha.ad0 = (const float*)d_in[4]; ha.b0 = (const float*)d_in[5];
    ha.W1 = (const float*)d_in[6];  ha.as1 = (const float*)d_in[7];
    ha.ad1 = (const float*)d_in[8]; ha.b1 = (const float*)d_in[9];
    ha.W2 = (const float*)d_in[10]; ha.as2 = (const float*)d_in[11];
    ha.ad2 = (const float*)d_in[12]; ha.b2 = (const float*)d_in[13];
    ha.W3 = (const float*)d_in[14]; ha.as3 = (const float*)d_in[15];
    ha.ad3 = (const float*)d_in[16]; ha.b3 = (const float*)d_in[17];
    ha.WT0 = WT0; ha.WT1 = WT1; ha.WT2 = WT2; ha.WT3 = WT3;
    ha.bar = bar; ha.cnt = cnt;
    ha.slot = slot; ha.offsR = offsR; ha.offs = offs;
    ha.adj = adj; ha.csum = csum;
    ha.sbuf = sbuf; ha.dbuf = dbuf; ha.Xb = Xb; ha.Yb = Yb;
    ha.dout = (float*)d_out;
    ha.N = N; ha.E = E; ha.XC = XC;

    // zero bar + cnt (contiguous in ws; one memset, re-runs on every replay)
    hipMemsetAsync(bar, 0, (size_t)(256 + (size_t)N * 4), stream);
    k_mega<<<GRID, 256, 0, stream>>>(ha);
}

// Round 10
// 298.912 us; speedup vs baseline: 6.1604x; 4.5272x over previous
//
#include <hip/hip_runtime.h>
#include <hip/hip_bf16.h>

#define LRELU_SLOPE 0.2f
#define WTOT 108544  // 65536 + 32768 + 8192 + 2048

typedef __attribute__((ext_vector_type(8))) short short8;
typedef __attribute__((ext_vector_type(4))) float f32x4;

__device__ __forceinline__ unsigned short bf16r(float f) {
    unsigned int u = __builtin_bit_cast(unsigned int, f);
    u += 0x7fffu + ((u >> 16) & 1u);   // RNE
    return (unsigned short)(u >> 16);
}
__device__ __forceinline__ float bf2f(unsigned short u) {
    return __builtin_bit_cast(float, (unsigned int)u << 16);
}

// async global->LDS 16B DMA
#define GLD16(g, l)                                                            \
    __builtin_amdgcn_global_load_lds(                                          \
        (const __attribute__((address_space(1))) void*)(g),                    \
        (__attribute__((address_space(3))) void*)(l), 16, 0, 0)

#define QB(v, k) __builtin_amdgcn_ds_swizzle((v), 0x8000 | ((k) * 0x55))

// ---------------- preamble: x->bf16 + W->WT bf16 transposed + edge count/slot ----------------

__global__ void k_pre(const float* __restrict__ x, unsigned short* __restrict__ Xb,
                      const float* __restrict__ Wa, const float* __restrict__ Wb,
                      const float* __restrict__ Wc, const float* __restrict__ Wd,
                      unsigned short* __restrict__ Ta, unsigned short* __restrict__ Tb,
                      unsigned short* __restrict__ Tc, unsigned short* __restrict__ Td,
                      const int* __restrict__ ei, int* __restrict__ cnt,
                      int* __restrict__ slot, int XC, int E) {
    int gid = blockIdx.x * blockDim.x + threadIdx.x;
    if (gid < XC) {
        const float4* xp = (const float4*)x + (long)gid * 2;
        float4 a = xp[0], b = xp[1];
        short8 pk;
        pk[0] = (short)bf16r(a.x); pk[1] = (short)bf16r(a.y);
        pk[2] = (short)bf16r(a.z); pk[3] = (short)bf16r(a.w);
        pk[4] = (short)bf16r(b.x); pk[5] = (short)bf16r(b.y);
        pk[6] = (short)bf16r(b.z); pk[7] = (short)bf16r(b.w);
        *(short8*)(Xb + (long)gid * 8) = pk;
        return;
    }
    int id = gid - XC;
    if (id < WTOT) {
        const float* W; unsigned short* T; int K, Nc;
        if (id < 65536)       { W = Wa; T = Ta; K = 256; Nc = 256; }
        else if (id < 98304)  { id -= 65536;  W = Wb; T = Tb; K = 256; Nc = 128; }
        else if (id < 106496) { id -= 98304;  W = Wc; T = Tc; K = 128; Nc = 64; }
        else                  { id -= 106496; W = Wd; T = Td; K = 64;  Nc = 32; }
        int n = id / K, k = id % K;
        T[id] = bf16r(W[(long)k * Nc + n]);
        return;
    }
    int e = id - WTOT;
    if (e >= E) return;
    int dst = ei[E + e];
    slot[e] = atomicAdd(&cnt[dst], 1);
}

// ---------------- CSR: block scan + (last block) top-level scan (r16, proven) ----------------

__global__ void k_scan_blk(const int* __restrict__ cnt, int* __restrict__ offsR,
                           int* __restrict__ bsum, int* __restrict__ bpre,
                           int* __restrict__ done, int N, int NB) {
    __shared__ int temp[1024];
    __shared__ int last_s;
    int t = threadIdx.x;
    int gi = blockIdx.x * 1024 + t;
    int v = (gi < N) ? cnt[gi] + 1 : 0;
    temp[t] = v;
    __syncthreads();
    for (int o = 1; o < 1024; o <<= 1) {
        int x = (t >= o) ? temp[t - o] : 0;
        __syncthreads();
        temp[t] += x;
        __syncthreads();
    }
    if (gi < N) offsR[gi] = temp[t] - v;
    if (t == 1023) bsum[blockIdx.x] = temp[1023];
    if (t == 0) {
        __threadfence();
        last_s = (atomicAdd(done, 1) == NB - 1) ? 1 : 0;
    }
    __syncthreads();
    if (last_s) {
        __threadfence();
        int v2 = (t < NB) ? bsum[t] : 0;
        temp[t] = v2;
        __syncthreads();
        for (int o = 1; o < 1024; o <<= 1) {
            int x = (t >= o) ? temp[t - o] : 0;
            __syncthreads();
            temp[t] += x;
            __syncthreads();
        }
        if (t < NB) bpre[t] = temp[t] - v2;
        if (t == NB - 1) bpre[NB] = temp[t];
    }
}

// ---------------- mg0 + folded finalize/scatter ----------------
// r20: k_finalize rides at the head of mg0 (independent of the GEMM; adj/offs
// consumers launch after the next kernel boundary). Saves one launch (~12us,
// A/B-measured R5->R6) and hides the scatter under mg0's DMA waits.
// GEMM body = r16 k_mgemm<64,256,4> verbatim (K-split KH=128, 32KB LDS).

__global__ __launch_bounds__(256) void k_mg0fin(
        const int* __restrict__ ei, const int* __restrict__ offsR,
        const int* __restrict__ bpre, const int* __restrict__ slot,
        int* __restrict__ offs, int* __restrict__ adj, int NB, int E,
        const unsigned short* __restrict__ Ab, const unsigned short* __restrict__ WT,
        unsigned short* __restrict__ Cb,
        const float* __restrict__ a_src, const float* __restrict__ a_dst,
        float* __restrict__ sbuf, float* __restrict__ dbuf,
        int M, int RB) {
    constexpr int KT = 256, BN = 64, GX = 4, KH = 128, NR = 2;
    constexpr int KITER = KH / 32;
    constexpr int NBF = BN / 16;
    constexpr int CPR = BN / 32;
    constexpr int SP  = BN + 8;
    constexpr int ASH = 64 * KH;          // shorts
    constexpr int CHR = KH / 8;
    constexpr int SHC = 4;                // log2(CHR)
    constexpr int AIT = CHR / 4;
    constexpr int BIT = BN * CHR / 256;
    __shared__ __align__(16) unsigned short LB[16384];   // 32 KB

    // ---- finalize + scatter (grid-stride; one iter at this grid size) ----
    {
        int gtid = blockIdx.x * 256 + threadIdx.x;
        int GT = gridDim.x * 256;
        int N = M;
        int NA = (N + 256) & ~255;
        for (int gi = gtid; gi < NA + E; gi += GT) {
            if (gi < NA) {
                if (gi < N) {
                    int v = offsR[gi] + bpre[gi >> 10];
                    offs[gi] = v;
                    adj[v] = gi;                       // self-loop at segment head
                } else if (gi == N) {
                    offs[N] = bpre[NB];
                }
            } else {
                int e = gi - NA;
                int dst = ei[E + e];
                adj[offsR[dst] + bpre[dst >> 10] + 1 + slot[e]] = ei[e];   // no atomics
            }
        }
    }

    // ---- GEMM (r16 verbatim) ----
    int id = blockIdx.x;
    int xcd = id & 7;
    int q  = id >> 3;
    int ct = q % GX;
    int rb = (q / GX) * 8 + xcd;
    if (rb >= RB) return;
    int bm = rb * 64, bn = ct * BN;

    int t = threadIdx.x;
    int wv = t >> 6, l = t & 63;
    int row_in = l & 15, quad = l >> 4;
    char* LBb = (char*)LB;
    const char* Agb = (const char*)Ab;
    const char* WTb = (const char*)WT;

    f32x4 acc[NBF];
#pragma unroll
    for (int j = 0; j < NBF; ++j) acc[j] = (f32x4){0.f, 0.f, 0.f, 0.f};

    int arow = wv * 16 + row_in;

#pragma unroll
    for (int r = 0; r < NR; ++r) {
        if (r > 0) __syncthreads();
#pragma unroll
        for (int i = 0; i < AIT; ++i) {
            int c = i * 256 + t;
            int row = c >> SHC;
            int ci  = c & (CHR - 1);
            int cis = ci ^ (row & 7);
            int grow = bm + row; if (grow >= M) grow = M - 1;
            long gb = (long)grow * (KT * 2) + r * (KH * 2) + cis * 16;
            GLD16(Agb + gb, LBb + (i * 256 + wv * 64) * 16);
        }
#pragma unroll
        for (int i = 0; i < BIT; ++i) {
            int c = i * 256 + t;
            int col = c >> SHC;
            int ci  = c & (CHR - 1);
            int cis = ci ^ (col & 7);
            long gb = (long)(bn + col) * (KT * 2) + r * (KH * 2) + cis * 16;
            GLD16(WTb + gb, LBb + ASH * 2 + (i * 256 + wv * 64) * 16);
        }
        asm volatile("s_waitcnt vmcnt(0)" ::: "memory");
        __syncthreads();

#pragma unroll
        for (int ki = 0; ki < KITER; ++ki) {
            int aoff = (arow * (KH * 2) + ki * 64 + quad * 16) ^ ((arow & 7) << 4);
            short8 av = *(const short8*)(LBb + aoff);
#pragma unroll
            for (int f = 0; f < NBF; ++f) {
                int bcol = f * 16 + row_in;
                int boff = ASH * 2 + ((bcol * (KH * 2) + ki * 64 + quad * 16) ^ ((bcol & 7) << 4));
                short8 bv = *(const short8*)(LBb + boff);
                acc[f] = __builtin_amdgcn_mfma_f32_16x16x32_bf16(av, bv, acc[f], 0, 0, 0);
            }
        }
    }
    __syncthreads();

#pragma unroll
    for (int r = 0; r < 4; ++r)
#pragma unroll
        for (int f = 0; f < NBF; ++f)
            LB[(wv * 16 + quad * 4 + r) * SP + f * 16 + row_in] = bf16r(acc[f][r]);
    __syncthreads();

    int rr = t / CPR, cc = t % CPR;
    if (rr < 64) {
        int grow = bm + rr;
        int colb = bn + cc * 32;
        if (grow < M) {
            const unsigned short* ep = &LB[rr * SP + cc * 32];
            short8 v0 = *(const short8*)(ep);
            short8 v1 = *(const short8*)(ep + 8);
            short8 v2 = *(const short8*)(ep + 16);
            short8 v3 = *(const short8*)(ep + 24);
            unsigned short* cp = &Cb[(long)grow * 256 + colb];
            *(short8*)(cp)      = v0;
            *(short8*)(cp + 8)  = v1;
            *(short8*)(cp + 16) = v2;
            *(short8*)(cp + 24) = v3;
            int hd = colb >> 5;
            const float* ap = a_src + hd * 32;
            const float* dp = a_dst + hd * 32;
            float ss = 0.f, dd = 0.f;
#pragma unroll
            for (int u = 0; u < 8; ++u) {
                float va = bf2f((unsigned short)v0[u]); ss += va * ap[u];      dd += va * dp[u];
                float vb = bf2f((unsigned short)v1[u]); ss += vb * ap[8 + u];  dd += vb * dp[8 + u];
                float vc = bf2f((unsigned short)v2[u]); ss += vc * ap[16 + u]; dd += vc * dp[16 + u];
                float vd = bf2f((unsigned short)v3[u]); ss += vd * ap[24 + u]; dd += vd * dp[24 + u];
            }
            sbuf[(long)grow * 8 + hd] = ss;
            dbuf[(long)grow * 8 + hd] = dd;
        }
    }
}

// ---------------- fused aggregate(L) + GEMM(L+1) ----------------
// r20: block owns 64 nodes. Phase 1: aggregate them (8-wide edge batches, r15
// structure - deeper MLP compensates the LDS-capped occupancy), ELU, write bf16
// activations DIRECTLY into the LDS A-tile (XOR-swizzled to match the MFMA
// ds_read). Phase 2: GEMM A(LDS) x WT(DMA-staged) -> next h + fused s/d.
// No grid dependency: gathers read the PREVIOUS kernel's output (boundary-
// synced); the GEMM consumes only this block's own 64 rows. Y/s/d ping-pong
// across layers prevents read/write races between blocks.

template<int HIN, int NC, int KH>
__global__ __launch_bounds__(256, 4) void k_agmg(
        const unsigned short* __restrict__ h,   // prev out, N x (HIN*32)
        const float* __restrict__ s, const float* __restrict__ dsc,
        const int* __restrict__ offs, const int* __restrict__ adj,
        const float* __restrict__ bias,         // layer-L bias (HIN*32)
        const unsigned short* __restrict__ WT,  // NC x KT
        unsigned short* __restrict__ Cb,        // out, N x NC
        const float* __restrict__ a_src, const float* __restrict__ a_dst,
        float* __restrict__ sb2, float* __restrict__ db2,   // out scores N x (NC/32)
        int N, int RB) {
    constexpr int KT   = HIN * 32;
    constexpr int NR   = KT / KH;
    constexpr int KITER = KH / 32;
    constexpr int NBF  = NC / 16;
    constexpr int CPR  = NC / 32;
    constexpr int SP   = NC + 8;
    constexpr int ASH2 = 64 * KT * 2;           // A bytes
    constexpr int CHR  = KH / 8;
    constexpr int BIT  = NC * CHR / 256;        // >=1 for all instantiations
    constexpr int HOUT = NC / 32;
    constexpr int TOT1 = ASH2 + NC * KH * 2;
    constexpr int TOT2 = 64 * SP * 2;
    __shared__ __align__(16) unsigned short LB[(TOT1 > TOT2 ? TOT1 : TOT2) / 2];

    int rb = blockIdx.x;
    if (rb >= RB) return;
    int bm = rb * 64;
    int t = threadIdx.x;
    char* LBb = (char*)LB;

    // ---- phase 1: aggregate 64 nodes -> LDS A-tile ----
    constexpr int UNITS = 64 * HIN * 4;
    for (int u = t; u < UNITS; u += 256) {
        int c8 = u & 3;                    // == t&3 -> quad-coop preserved
        int hh = (u >> 2) % HIN;
        int nl = u / (4 * HIN);
        int n0 = bm + nl;
        int nn = n0 < N ? n0 : N - 1;      // tail rows: duplicate data, store-masked
        int beg = offs[nn], end = offs[nn + 1];
        float dn = dsc[nn * HIN + hh];
        int coff = hh * 32 + c8 * 8;
        const unsigned short* hb = h + coff;

        float denom = 0.f;
        float acc[8];
#pragma unroll
        for (int z = 0; z < 8; ++z) acc[z] = 0.f;

        for (int j = beg; j < end; j += 8) {
            int my0 = j + c8;
            int my1 = my0 + 4;
            int i0 = my0 < end ? my0 : end - 1;
            int i1 = my1 < end ? my1 : end - 1;
            int p  = adj[i0];
            int qn = adj[i1];
            int a0 = QB(p, 0),  a1 = QB(p, 1),  a2 = QB(p, 2),  a3 = QB(p, 3);
            int b0 = QB(qn, 0), b1 = QB(qn, 1), b2 = QB(qn, 2), b3 = QB(qn, 3);
            short8 h0 = *(const short8*)(hb + (size_t)a0 * KT);
            short8 h1 = *(const short8*)(hb + (size_t)a1 * KT);
            short8 h2 = *(const short8*)(hb + (size_t)a2 * KT);
            short8 h3 = *(const short8*)(hb + (size_t)a3 * KT);
            short8 h4 = *(const short8*)(hb + (size_t)b0 * KT);
            short8 h5 = *(const short8*)(hb + (size_t)b1 * KT);
            short8 h6 = *(const short8*)(hb + (size_t)b2 * KT);
            short8 h7 = *(const short8*)(hb + (size_t)b3 * KT);
            float e0 = s[p * HIN + hh] + dn;
            float e1 = s[qn * HIN + hh] + dn;
            e0 = e0 > 0.f ? e0 : LRELU_SLOPE * e0;
            e1 = e1 > 0.f ? e1 : LRELU_SLOPE * e1;
            float wA = __expf(fminf(e0, 80.f));
            float wB = __expf(fminf(e1, 80.f));
            if (my0 >= end) wA = 0.f;
            if (my1 >= end) wB = 0.f;
            int wiA = __builtin_bit_cast(int, wA);
            int wiB = __builtin_bit_cast(int, wB);
            float w0 = __builtin_bit_cast(float, QB(wiA, 0));
            float w1 = __builtin_bit_cast(float, QB(wiA, 1));
            float w2 = __builtin_bit_cast(float, QB(wiA, 2));
            float w3 = __builtin_bit_cast(float, QB(wiA, 3));
            float w4 = __builtin_bit_cast(float, QB(wiB, 0));
            float w5 = __builtin_bit_cast(float, QB(wiB, 1));
            float w6 = __builtin_bit_cast(float, QB(wiB, 2));
            float w7 = __builtin_bit_cast(float, QB(wiB, 3));
            denom += ((w0 + w1) + (w2 + w3)) + ((w4 + w5) + (w6 + w7));
#pragma unroll
            for (int z = 0; z < 8; ++z) {
                float aa = w0 * bf2f((unsigned short)h0[z]) + w1 * bf2f((unsigned short)h1[z]);
                float ab = w2 * bf2f((unsigned short)h2[z]) + w3 * bf2f((unsigned short)h3[z]);
                float ac = w4 * bf2f((unsigned short)h4[z]) + w5 * bf2f((unsigned short)h5[z]);
                float ad = w6 * bf2f((unsigned short)h6[z]) + w7 * bf2f((unsigned short)h7[z]);
                acc[z] += (aa + ab) + (ac + ad);
            }
        }

        float inv = 1.0f / denom;
        short8 pk;
#pragma unroll
        for (int z = 0; z < 8; ++z) {
            float o = acc[z] * inv + bias[coff + z];
            float v = o > 0.f ? o : (__expf(o) - 1.f);   // ELU
            pk[z] = (short)bf16r(v);
        }
        int lbyte = (nl * (KT * 2) + coff * 2) ^ ((nl & 7) << 4);
        *(short8*)(LBb + lbyte) = pk;
    }
    __syncthreads();

    // ---- phase 2: GEMM A(LDS, full K) x B(DMA-staged per KH round) ----
    int wv = t >> 6, l = t & 63;
    int row_in = l & 15, quad = l >> 4;
    int arow = wv * 16 + row_in;
    const char* WTb = (const char*)WT;

    f32x4 gac[NBF];
#pragma unroll
    for (int j = 0; j < NBF; ++j) gac[j] = (f32x4){0.f, 0.f, 0.f, 0.f};

#pragma unroll
    for (int r = 0; r < NR; ++r) {
        if (r > 0) __syncthreads();
#pragma unroll
        for (int i = 0; i < BIT; ++i) {
            int c = i * 256 + t;
            int col = c / CHR;
            int ci  = c % CHR;
            int cis = ci ^ (col & 7);
            long gb = (long)col * (KT * 2) + r * (KH * 2) + cis * 16;
            GLD16(WTb + gb, LBb + ASH2 + (i * 256 + wv * 64) * 16);
        }
        asm volatile("s_waitcnt vmcnt(0)" ::: "memory");
        __syncthreads();

#pragma unroll
        for (int ki = 0; ki < KITER; ++ki) {
            int aoff = (arow * (KT * 2) + r * (KH * 2) + ki * 64 + quad * 16) ^ ((arow & 7) << 4);
            short8 av = *(const short8*)(LBb + aoff);
#pragma unroll
            for (int f = 0; f < NBF; ++f) {
                int bcol = f * 16 + row_in;
                int boff = ASH2 + ((bcol * (KH * 2) + ki * 64 + quad * 16) ^ ((bcol & 7) << 4));
                short8 bv = *(const short8*)(LBb + boff);
                gac[f] = __builtin_amdgcn_mfma_f32_16x16x32_bf16(av, bv, gac[f], 0, 0, 0);
            }
        }
    }
    __syncthreads();

    // ---- epilogue: LDS repack -> coalesced stores + fused s/d (layer L+1) ----
#pragma unroll
    for (int r4 = 0; r4 < 4; ++r4)
#pragma unroll
        for (int f = 0; f < NBF; ++f)
            LB[(wv * 16 + quad * 4 + r4) * SP + f * 16 + row_in] = bf16r(gac[f][r4]);
    __syncthreads();

    int rr = t / CPR, cc = t % CPR;
    if (rr < 64) {
        int grow = bm + rr;
        int colb = cc * 32;
        if (grow < N) {
            const unsigned short* ep = &LB[rr * SP + colb];
            short8 v0 = *(const short8*)(ep);
            short8 v1 = *(const short8*)(ep + 8);
            short8 v2 = *(const short8*)(ep + 16);
            short8 v3 = *(const short8*)(ep + 24);
            unsigned short* cp = &Cb[(long)grow * NC + colb];
            *(short8*)(cp)      = v0;
            *(short8*)(cp + 8)  = v1;
            *(short8*)(cp + 16) = v2;
            *(short8*)(cp + 24) = v3;
            int hd = colb >> 5;
            const float* ap = a_src + hd * 32;
            const float* dp = a_dst + hd * 32;
            float ss = 0.f, dd = 0.f;
#pragma unroll
            for (int u = 0; u < 8; ++u) {
                float va = bf2f((unsigned short)v0[u]); ss += va * ap[u];      dd += va * dp[u];
                float vb = bf2f((unsigned short)v1[u]); ss += vb * ap[8 + u];  dd += vb * dp[8 + u];
                float vc = bf2f((unsigned short)v2[u]); ss += vc * ap[16 + u]; dd += vc * dp[16 + u];
                float vd = bf2f((unsigned short)v3[u]); ss += vd * ap[24 + u]; dd += vd * dp[24 + u];
            }
            sb2[(long)grow * HOUT + hd] = ss;
            db2[(long)grow * HOUT + hd] = dd;
        }
    }
}

// ---------------- final aggregate (H=1): r13 4-wide + log_softmax ----------------

__global__ void k_aggf_fin(const unsigned short* __restrict__ h, const float* __restrict__ s,
                           const float* __restrict__ dsc, const int* __restrict__ offs,
                           const int* __restrict__ adj, const float* __restrict__ bias,
                           float* __restrict__ out32, int N) {
    const int H = 1, C8 = 4, HC = 32;
    long tid = (long)blockIdx.x * blockDim.x + threadIdx.x;
    if (tid >= (long)N * C8) return;
    int c8 = (int)(tid % C8);
    int n  = (int)(tid / C8);
    int beg = offs[n], end = offs[n + 1];
    float dn = dsc[n * H];
    int coff = c8 * 8;
    const unsigned short* hb = h + coff;

    float denom = 0.f;
    float acc[8];
#pragma unroll
    for (int u = 0; u < 8; ++u) acc[u] = 0.f;

    for (int j = beg; j < end; j += 4) {
        int my = j + c8;
        int idx = my < end ? my : end - 1;
        int sn = adj[idx];
        float e = s[sn * H] + dn;
        e = e > 0.f ? e : LRELU_SLOPE * e;
        float w = __expf(fminf(e, 80.f));
        if (my >= end) w = 0.f;
        int wi = __builtin_bit_cast(int, w);
        int sn0 = QB(sn, 0);
        int sn1 = QB(sn, 1);
        int sn2 = QB(sn, 2);
        int sn3 = QB(sn, 3);
        float w0 = __builtin_bit_cast(float, QB(wi, 0));
        float w1 = __builtin_bit_cast(float, QB(wi, 1));
        float w2 = __builtin_bit_cast(float, QB(wi, 2));
        float w3 = __builtin_bit_cast(float, QB(wi, 3));
        short8 h0 = *(const short8*)(hb + (size_t)sn0 * HC);
        short8 h1 = *(const short8*)(hb + (size_t)sn1 * HC);
        short8 h2 = *(const short8*)(hb + (size_t)sn2 * HC);
        short8 h3 = *(const short8*)(hb + (size_t)sn3 * HC);
        denom += (w0 + w1) + (w2 + w3);
#pragma unroll
        for (int u = 0; u < 8; ++u) {
            float a01 = w0 * bf2f((unsigned short)h0[u]) + w1 * bf2f((unsigned short)h1[u]);
            float a23 = w2 * bf2f((unsigned short)h2[u]) + w3 * bf2f((unsigned short)h3[u]);
            acc[u] += a01 + a23;
        }
    }

    float inv = 1.0f / denom;
    float o[8];
#pragma unroll
    for (int u = 0; u < 8; ++u) o[u] = acc[u] * inv + bias[coff + u];

    float m = o[0];
#pragma unroll
    for (int u = 1; u < 8; ++u) m = fmaxf(m, o[u]);
    m = fmaxf(m, __shfl_xor(m, 1));
    m = fmaxf(m, __shfl_xor(m, 2));
    float ssum = 0.f;
#pragma unroll
    for (int u = 0; u < 8; ++u) ssum += __expf(o[u] - m);
    ssum += __shfl_xor(ssum, 1);
    ssum += __shfl_xor(ssum, 2);
    float lse = m + __logf(ssum);
    float4 lo = {o[0] - lse, o[1] - lse, o[2] - lse, o[3] - lse};
    float4 hi = {o[4] - lse, o[5] - lse, o[6] - lse, o[7] - lse};
    *(float4*)(out32 + tid * 8)     = lo;
    *(float4*)(out32 + tid * 8 + 4) = hi;
}

// ---------------- host ----------------

static inline size_t align_up(size_t x) { return (x + 255) & ~(size_t)255; }

extern "C" void kernel_launch(void* const* d_in, const int* in_sizes, int n_in,
                              void* d_out, int out_size, void* d_ws, size_t ws_size,
                              hipStream_t stream) {
    const float* x   = (const float*)d_in[0];
    const int*   ei  = (const int*)d_in[1];

    const int N = in_sizes[0] / 256;   // 50000
    const int E = in_sizes[1] / 2;     // 400000
    const int ET = E + N;
    const int NB = (N + 1023) / 1024;
    const int XC = N * 32;

    size_t off = 0;
    char* ws = (char*)d_ws;
    auto take = [&](size_t bytes) { char* p = ws + off; off += align_up(bytes); return p; };
    int*   cntd  = (int*)take((size_t)(N + 1) * 4);   // cnt[N] + done flag (one memset)
    int*   offs  = (int*)take((size_t)(N + 1) * 4);
    int*   offsR = (int*)take((size_t)(N + 1) * 4);
    int*   slot  = (int*)take((size_t)E * 4);
    int*   adj   = (int*)take((size_t)ET * 4);
    int*   bsum  = (int*)take((size_t)(NB + 1) * 4);
    int*   bpre  = (int*)take((size_t)(NB + 1) * 4);
    float* s0    = (float*)take((size_t)N * 8 * 4);
    float* d0    = (float*)take((size_t)N * 8 * 4);
    float* s1    = (float*)take((size_t)N * 4 * 4);
    float* d1    = (float*)take((size_t)N * 4 * 4);
    unsigned short* Xb = (unsigned short*)take((size_t)N * 256 * 2);
    unsigned short* Y0 = (unsigned short*)take((size_t)N * 256 * 2);
    unsigned short* Y1 = (unsigned short*)take((size_t)N * 128 * 2);
    unsigned short* WT0 = (unsigned short*)take((size_t)256 * 256 * 2);
    unsigned short* WT1 = (unsigned short*)take((size_t)256 * 128 * 2);
    unsigned short* WT2 = (unsigned short*)take((size_t)128 * 64 * 2);
    unsigned short* WT3 = (unsigned short*)take((size_t)64 * 32 * 2);
    (void)ws_size;

    int* cnt  = cntd;
    int* done = cntd + N;

    const float* as_[4] = {(const float*)d_in[3], (const float*)d_in[7],
                           (const float*)d_in[11], (const float*)d_in[15]};
    const float* ad_[4] = {(const float*)d_in[4], (const float*)d_in[8],
                           (const float*)d_in[12], (const float*)d_in[16]};
    const float* b_[4]  = {(const float*)d_in[5], (const float*)d_in[9],
                           (const float*)d_in[13], (const float*)d_in[17]};

    const int RB  = (N + 63) / 64;         // 782
    const int RBp = ((RB + 7) / 8) * 8;    // 784

    // 1. zero cnt+done
    hipMemsetAsync(cntd, 0, (size_t)(N + 1) * 4, stream);
    // 2. preamble
    {
        long tot = (long)XC + WTOT + E;
        k_pre<<<(int)((tot + 255) / 256), 256, 0, stream>>>(
            x, Xb,
            (const float*)d_in[2], (const float*)d_in[6], (const float*)d_in[10],
            (const float*)d_in[14], WT0, WT1, WT2, WT3, ei, cnt, slot, XC, E);
    }
    // 3. scan (block + last-done top scan)
    k_scan_blk<<<NB, 1024, 0, stream>>>(cnt, offsR, bsum, bpre, done, N, NB);
    // 4. finalize/scatter + GEMM L0 (fused)
    k_mg0fin<<<4 * RBp, 256, 0, stream>>>(
        ei, offsR, bpre, slot, offs, adj, NB, E,
        Xb, WT0, Y0, as_[0], ad_[0], s0, d0, N, RB);
    // 5-7. fused aggregate(L) + GEMM(L+1), ping-pong buffers
    k_agmg<8, 128, 64><<<RB, 256, 0, stream>>>(
        Y0, s0, d0, offs, adj, b_[0], WT1, Y1, as_[1], ad_[1], s1, d1, N, RB);
    k_agmg<4, 64, 128><<<RB, 256, 0, stream>>>(
        Y1, s1, d1, offs, adj, b_[1], WT2, Y0, as_[2], ad_[2], s0, d0, N, RB);
    k_agmg<2, 32, 64><<<RB, 256, 0, stream>>>(
        Y0, s0, d0, offs, adj, b_[2], WT3, Y1, as_[3], ad_[3], s1, d1, N, RB);
    // 8. final aggregate + log_softmax
    k_aggf_fin<<<(int)(((long)N * 4 + 255) / 256), 256, 0, stream>>>(
        Y1, s1, d1, offs, adj, b_[3], (float*)d_out, N);
}

// Round 11
// 297.067 us; speedup vs baseline: 6.1987x; 1.0062x over previous
//
#include <hip/hip_runtime.h>
#include <hip/hip_bf16.h>

#define LRELU_SLOPE 0.2f
#define WTOT 108544  // 65536 + 32768 + 8192 + 2048

typedef __attribute__((ext_vector_type(8))) short short8;
typedef __attribute__((ext_vector_type(4))) float f32x4;

__device__ __forceinline__ unsigned short bf16r(float f) {
    unsigned int u = __builtin_bit_cast(unsigned int, f);
    u += 0x7fffu + ((u >> 16) & 1u);   // RNE
    return (unsigned short)(u >> 16);
}
__device__ __forceinline__ float bf2f(unsigned short u) {
    return __builtin_bit_cast(float, (unsigned int)u << 16);
}

// async global->LDS 16B DMA
#define GLD16(g, l)                                                            \
    __builtin_amdgcn_global_load_lds(                                          \
        (const __attribute__((address_space(1))) void*)(g),                    \
        (__attribute__((address_space(3))) void*)(l), 16, 0, 0)

#define QB(v, k) __builtin_amdgcn_ds_swizzle((v), 0x8000 | ((k) * 0x55))

// ---------------- preamble: x->bf16 + W->WT bf16 transposed + edge count/slot ----------------

__global__ void k_pre(const float* __restrict__ x, unsigned short* __restrict__ Xb,
                      const float* __restrict__ Wa, const float* __restrict__ Wb,
                      const float* __restrict__ Wc, const float* __restrict__ Wd,
                      unsigned short* __restrict__ Ta, unsigned short* __restrict__ Tb,
                      unsigned short* __restrict__ Tc, unsigned short* __restrict__ Td,
                      const int* __restrict__ ei, int* __restrict__ cnt,
                      int* __restrict__ slot, int XC, int E) {
    int gid = blockIdx.x * blockDim.x + threadIdx.x;
    if (gid < XC) {
        const float4* xp = (const float4*)x + (long)gid * 2;
        float4 a = xp[0], b = xp[1];
        short8 pk;
        pk[0] = (short)bf16r(a.x); pk[1] = (short)bf16r(a.y);
        pk[2] = (short)bf16r(a.z); pk[3] = (short)bf16r(a.w);
        pk[4] = (short)bf16r(b.x); pk[5] = (short)bf16r(b.y);
        pk[6] = (short)bf16r(b.z); pk[7] = (short)bf16r(b.w);
        *(short8*)(Xb + (long)gid * 8) = pk;
        return;
    }
    int id = gid - XC;
    if (id < WTOT) {
        const float* W; unsigned short* T; int K, Nc;
        if (id < 65536)       { W = Wa; T = Ta; K = 256; Nc = 256; }
        else if (id < 98304)  { id -= 65536;  W = Wb; T = Tb; K = 256; Nc = 128; }
        else if (id < 106496) { id -= 98304;  W = Wc; T = Tc; K = 128; Nc = 64; }
        else                  { id -= 106496; W = Wd; T = Td; K = 64;  Nc = 32; }
        int n = id / K, k = id % K;
        T[id] = bf16r(W[(long)k * Nc + n]);
        return;
    }
    int e = id - WTOT;
    if (e >= E) return;
    int dst = ei[E + e];
    slot[e] = atomicAdd(&cnt[dst], 1);
}

// ---------------- CSR: block scan + (last block) top-level scan (r16, proven) ----------------

__global__ void k_scan_blk(const int* __restrict__ cnt, int* __restrict__ offsR,
                           int* __restrict__ bsum, int* __restrict__ bpre,
                           int* __restrict__ done, int N, int NB) {
    __shared__ int temp[1024];
    __shared__ int last_s;
    int t = threadIdx.x;
    int gi = blockIdx.x * 1024 + t;
    int v = (gi < N) ? cnt[gi] + 1 : 0;
    temp[t] = v;
    __syncthreads();
    for (int o = 1; o < 1024; o <<= 1) {
        int x = (t >= o) ? temp[t - o] : 0;
        __syncthreads();
        temp[t] += x;
        __syncthreads();
    }
    if (gi < N) offsR[gi] = temp[t] - v;
    if (t == 1023) bsum[blockIdx.x] = temp[1023];
    if (t == 0) {
        __threadfence();
        last_s = (atomicAdd(done, 1) == NB - 1) ? 1 : 0;
    }
    __syncthreads();
    if (last_s) {
        __threadfence();
        int v2 = (t < NB) ? bsum[t] : 0;
        temp[t] = v2;
        __syncthreads();
        for (int o = 1; o < 1024; o <<= 1) {
            int x = (t >= o) ? temp[t - o] : 0;
            __syncthreads();
            temp[t] += x;
            __syncthreads();
        }
        if (t < NB) bpre[t] = temp[t] - v2;
        if (t == NB - 1) bpre[NB] = temp[t];
    }
}

// ---------------- standalone mgemm (r16 K-split DMA, proven) ----------------

template<int BN, int KT, int GX>
__global__ __launch_bounds__(256) void k_mgemm(const unsigned short* __restrict__ Ab,
                                               const unsigned short* __restrict__ WT,
                                               unsigned short* __restrict__ Cb,
                                               const float* __restrict__ a_src,
                                               const float* __restrict__ a_dst,
                                               float* __restrict__ sbuf,
                                               float* __restrict__ dbuf,
                                               int M, int Nc, int H, int RB) {
    constexpr int KH   = (KT == 256) ? 128 : KT;
    constexpr int NR   = KT / KH;
    constexpr int KITER = KH / 32;
    constexpr int NBF = BN / 16;
    constexpr int CPR = BN / 32;
    constexpr int SP  = BN + 8;
    constexpr int ASH = 64 * KH;
    constexpr int BSH = BN * KH;
    constexpr int EPIL = 64 * SP;
    constexpr int LBSZ = (ASH + BSH) > EPIL ? (ASH + BSH) : EPIL;
    constexpr int CHR = KH / 8;
    constexpr int SHC = (KH == 128) ? 4 : 3;
    constexpr int AIT = CHR / 4;
    constexpr int BIT = BN * CHR / 256;
    __shared__ __align__(16) unsigned short LB[LBSZ];

    int id = blockIdx.x;
    int xcd = id & 7;
    int q  = id >> 3;
    int ct = q % GX;
    int rb = (q / GX) * 8 + xcd;
    if (rb >= RB) return;
    int bm = rb * 64, bn = ct * BN;

    int t = threadIdx.x;
    int wv = t >> 6, l = t & 63;
    int row_in = l & 15, quad = l >> 4;
    char* LBb = (char*)LB;
    const char* Agb = (const char*)Ab;
    const char* WTb = (const char*)WT;

    f32x4 acc[NBF];
#pragma unroll
    for (int j = 0; j < NBF; ++j) acc[j] = (f32x4){0.f, 0.f, 0.f, 0.f};

    int arow = wv * 16 + row_in;

#pragma unroll
    for (int r = 0; r < NR; ++r) {
        if (r > 0) __syncthreads();
#pragma unroll
        for (int i = 0; i < AIT; ++i) {
            int c = i * 256 + t;
            int row = c >> SHC;
            int ci  = c & (CHR - 1);
            int cis = ci ^ (row & 7);
            int grow = bm + row; if (grow >= M) grow = M - 1;
            long gb = (long)grow * (KT * 2) + r * (KH * 2) + cis * 16;
            GLD16(Agb + gb, LBb + (i * 256 + wv * 64) * 16);
        }
#pragma unroll
        for (int i = 0; i < BIT; ++i) {
            int c = i * 256 + t;
            int col = c >> SHC;
            int ci  = c & (CHR - 1);
            int cis = ci ^ (col & 7);
            long gb = (long)(bn + col) * (KT * 2) + r * (KH * 2) + cis * 16;
            GLD16(WTb + gb, LBb + ASH * 2 + (i * 256 + wv * 64) * 16);
        }
        asm volatile("s_waitcnt vmcnt(0)" ::: "memory");
        __syncthreads();

#pragma unroll
        for (int ki = 0; ki < KITER; ++ki) {
            int aoff = (arow * (KH * 2) + ki * 64 + quad * 16) ^ ((arow & 7) << 4);
            short8 av = *(const short8*)(LBb + aoff);
#pragma unroll
            for (int f = 0; f < NBF; ++f) {
                int bcol = f * 16 + row_in;
                int boff = ASH * 2 + ((bcol * (KH * 2) + ki * 64 + quad * 16) ^ ((bcol & 7) << 4));
                short8 bv = *(const short8*)(LBb + boff);
                acc[f] = __builtin_amdgcn_mfma_f32_16x16x32_bf16(av, bv, acc[f], 0, 0, 0);
            }
        }
    }
    __syncthreads();

#pragma unroll
    for (int r = 0; r < 4; ++r)
#pragma unroll
        for (int f = 0; f < NBF; ++f)
            LB[(wv * 16 + quad * 4 + r) * SP + f * 16 + row_in] = bf16r(acc[f][r]);
    __syncthreads();

    int rr = t / CPR, cc = t % CPR;
    if (rr < 64) {
        int grow = bm + rr;
        int colb = bn + cc * 32;
        if (grow < M && colb < Nc) {
            const unsigned short* ep = &LB[rr * SP + cc * 32];
            short8 v0 = *(const short8*)(ep);
            short8 v1 = *(const short8*)(ep + 8);
            short8 v2 = *(const short8*)(ep + 16);
            short8 v3 = *(const short8*)(ep + 24);
            unsigned short* cp = &Cb[(long)grow * Nc + colb];
            *(short8*)(cp)      = v0;
            *(short8*)(cp + 8)  = v1;
            *(short8*)(cp + 16) = v2;
            *(short8*)(cp + 24) = v3;
            int hd = colb >> 5;
            const float* ap = a_src + hd * 32;
            const float* dp = a_dst + hd * 32;
            float ss = 0.f, dd = 0.f;
#pragma unroll
            for (int u = 0; u < 8; ++u) {
                float va = bf2f((unsigned short)v0[u]); ss += va * ap[u];      dd += va * dp[u];
                float vb = bf2f((unsigned short)v1[u]); ss += vb * ap[8 + u];  dd += vb * dp[8 + u];
                float vc = bf2f((unsigned short)v2[u]); ss += vc * ap[16 + u]; dd += vc * dp[16 + u];
                float vd = bf2f((unsigned short)v3[u]); ss += vd * ap[24 + u]; dd += vd * dp[24 + u];
            }
            sbuf[(long)grow * H + hd] = ss;
            dbuf[(long)grow * H + hd] = dd;
        }
    }
}

// ---------------- mg0 + folded finalize/scatter (r20, proven) ----------------

__global__ __launch_bounds__(256) void k_mg0fin(
        const int* __restrict__ ei, const int* __restrict__ offsR,
        const int* __restrict__ bpre, const int* __restrict__ slot,
        int* __restrict__ offs, int* __restrict__ adj, int NB, int E,
        const unsigned short* __restrict__ Ab, const unsigned short* __restrict__ WT,
        unsigned short* __restrict__ Cb,
        const float* __restrict__ a_src, const float* __restrict__ a_dst,
        float* __restrict__ sbuf, float* __restrict__ dbuf,
        int M, int RB) {
    constexpr int KT = 256, BN = 64, GX = 4, KH = 128, NR = 2;
    constexpr int KITER = KH / 32;
    constexpr int NBF = BN / 16;
    constexpr int CPR = BN / 32;
    constexpr int SP  = BN + 8;
    constexpr int ASH = 64 * KH;
    constexpr int CHR = KH / 8;
    constexpr int SHC = 4;
    constexpr int AIT = CHR / 4;
    constexpr int BIT = BN * CHR / 256;
    __shared__ __align__(16) unsigned short LB[16384];

    // finalize + scatter (grid-stride)
    {
        int gtid = blockIdx.x * 256 + threadIdx.x;
        int GT = gridDim.x * 256;
        int N = M;
        int NA = (N + 256) & ~255;
        for (int gi = gtid; gi < NA + E; gi += GT) {
            if (gi < NA) {
                if (gi < N) {
                    int v = offsR[gi] + bpre[gi >> 10];
                    offs[gi] = v;
                    adj[v] = gi;
                } else if (gi == N) {
                    offs[N] = bpre[NB];
                }
            } else {
                int e = gi - NA;
                int dst = ei[E + e];
                adj[offsR[dst] + bpre[dst >> 10] + 1 + slot[e]] = ei[e];
            }
        }
    }

    // GEMM (r16 verbatim)
    int id = blockIdx.x;
    int xcd = id & 7;
    int q  = id >> 3;
    int ct = q % GX;
    int rb = (q / GX) * 8 + xcd;
    if (rb >= RB) return;
    int bm = rb * 64, bn = ct * BN;

    int t = threadIdx.x;
    int wv = t >> 6, l = t & 63;
    int row_in = l & 15, quad = l >> 4;
    char* LBb = (char*)LB;
    const char* Agb = (const char*)Ab;
    const char* WTb = (const char*)WT;

    f32x4 acc[NBF];
#pragma unroll
    for (int j = 0; j < NBF; ++j) acc[j] = (f32x4){0.f, 0.f, 0.f, 0.f};

    int arow = wv * 16 + row_in;

#pragma unroll
    for (int r = 0; r < NR; ++r) {
        if (r > 0) __syncthreads();
#pragma unroll
        for (int i = 0; i < AIT; ++i) {
            int c = i * 256 + t;
            int row = c >> SHC;
            int ci  = c & (CHR - 1);
            int cis = ci ^ (row & 7);
            int grow = bm + row; if (grow >= M) grow = M - 1;
            long gb = (long)grow * (KT * 2) + r * (KH * 2) + cis * 16;
            GLD16(Agb + gb, LBb + (i * 256 + wv * 64) * 16);
        }
#pragma unroll
        for (int i = 0; i < BIT; ++i) {
            int c = i * 256 + t;
            int col = c >> SHC;
            int ci  = c & (CHR - 1);
            int cis = ci ^ (col & 7);
            long gb = (long)(bn + col) * (KT * 2) + r * (KH * 2) + cis * 16;
            GLD16(WTb + gb, LBb + ASH * 2 + (i * 256 + wv * 64) * 16);
        }
        asm volatile("s_waitcnt vmcnt(0)" ::: "memory");
        __syncthreads();

#pragma unroll
        for (int ki = 0; ki < KITER; ++ki) {
            int aoff = (arow * (KH * 2) + ki * 64 + quad * 16) ^ ((arow & 7) << 4);
            short8 av = *(const short8*)(LBb + aoff);
#pragma unroll
            for (int f = 0; f < NBF; ++f) {
                int bcol = f * 16 + row_in;
                int boff = ASH * 2 + ((bcol * (KH * 2) + ki * 64 + quad * 16) ^ ((bcol & 7) << 4));
                short8 bv = *(const short8*)(LBb + boff);
                acc[f] = __builtin_amdgcn_mfma_f32_16x16x32_bf16(av, bv, acc[f], 0, 0, 0);
            }
        }
    }
    __syncthreads();

#pragma unroll
    for (int r = 0; r < 4; ++r)
#pragma unroll
        for (int f = 0; f < NBF; ++f)
            LB[(wv * 16 + quad * 4 + r) * SP + f * 16 + row_in] = bf16r(acc[f][r]);
    __syncthreads();

    int rr = t / CPR, cc = t % CPR;
    if (rr < 64) {
        int grow = bm + rr;
        int colb = bn + cc * 32;
        if (grow < M) {
            const unsigned short* ep = &LB[rr * SP + cc * 32];
            short8 v0 = *(const short8*)(ep);
            short8 v1 = *(const short8*)(ep + 8);
            short8 v2 = *(const short8*)(ep + 16);
            short8 v3 = *(const short8*)(ep + 24);
            unsigned short* cp = &Cb[(long)grow * 256 + colb];
            *(short8*)(cp)      = v0;
            *(short8*)(cp + 8)  = v1;
            *(short8*)(cp + 16) = v2;
            *(short8*)(cp + 24) = v3;
            int hd = colb >> 5;
            const float* ap = a_src + hd * 32;
            const float* dp = a_dst + hd * 32;
            float ss = 0.f, dd = 0.f;
#pragma unroll
            for (int u = 0; u < 8; ++u) {
                float va = bf2f((unsigned short)v0[u]); ss += va * ap[u];      dd += va * dp[u];
                float vb = bf2f((unsigned short)v1[u]); ss += vb * ap[8 + u];  dd += vb * dp[8 + u];
                float vc = bf2f((unsigned short)v2[u]); ss += vc * ap[16 + u]; dd += vc * dp[16 + u];
                float vd = bf2f((unsigned short)v3[u]); ss += vd * ap[24 + u]; dd += vd * dp[24 + u];
            }
            sbuf[(long)grow * 8 + hd] = ss;
            dbuf[(long)grow * 8 + hd] = dd;
        }
    }
}

// ---------------- wave-per-node aggregate (r21) ----------------
// GRP = H*8 lanes own one node: lane covers 4 channels (8B); one edge gather =
// the group reads ONE contiguous h-row (L0: 512B = 4 cache lines = 4 L1 txns
// vs 16 for the quad-scattered layout). Scores: lane's head = gl/8, so
// s[sn*H+hh] is a 32B broadcast-ish load; no cross-lane ops at all (denom is
// per-lane redundant). 4-edge unroll for MLP; no LDS -> full occupancy.
// Pre-commit: faster => aggf was L1-txn-bound; flat => fabric-BW-bound, done.

template<int H>
__global__ void k_aggw(const unsigned short* __restrict__ h, const float* __restrict__ s,
                       const float* __restrict__ dsc, const int* __restrict__ offs,
                       const int* __restrict__ adj, const float* __restrict__ bias,
                       unsigned short* __restrict__ out16, int N) {
    constexpr int HC  = H * 32;       // channels per node
    constexpr int GRP = H * 8;        // lanes per node
    constexpr int NPW = 64 / GRP;     // nodes per wave
    constexpr int NPB = 4 * NPW;      // nodes per block
    int t = threadIdx.x;
    int wv = t >> 6, lane = t & 63;
    int g  = lane / GRP;
    int gl = lane % GRP;
    int hh = gl >> 3;
    int n0 = blockIdx.x * NPB + wv * NPW + g;
    int n  = n0 < N ? n0 : N - 1;
    int beg = offs[n], end = offs[n + 1];
    float dn = dsc[n * H + hh];
    int coff = gl * 4;
    const unsigned short* hb = h + coff;

    float denom = 0.f;
    float a0 = 0.f, a1 = 0.f, a2 = 0.f, a3 = 0.f;

    for (int j = beg; j < end; j += 4) {
        int i1 = j + 1 < end ? j + 1 : end - 1;
        int i2 = j + 2 < end ? j + 2 : end - 1;
        int i3 = j + 3 < end ? j + 3 : end - 1;
        int sn0 = adj[j];
        int sn1 = adj[i1];
        int sn2 = adj[i2];
        int sn3 = adj[i3];
        // 4 independent contiguous row reads (8B/lane; group covers full row)
        ushort4 h0 = *(const ushort4*)(hb + (size_t)sn0 * HC);
        ushort4 h1 = *(const ushort4*)(hb + (size_t)sn1 * HC);
        ushort4 h2 = *(const ushort4*)(hb + (size_t)sn2 * HC);
        ushort4 h3 = *(const ushort4*)(hb + (size_t)sn3 * HC);
        float e0 = s[sn0 * H + hh] + dn;
        float e1 = s[sn1 * H + hh] + dn;
        float e2 = s[sn2 * H + hh] + dn;
        float e3 = s[sn3 * H + hh] + dn;
        e0 = e0 > 0.f ? e0 : LRELU_SLOPE * e0;
        e1 = e1 > 0.f ? e1 : LRELU_SLOPE * e1;
        e2 = e2 > 0.f ? e2 : LRELU_SLOPE * e2;
        e3 = e3 > 0.f ? e3 : LRELU_SLOPE * e3;
        float w0 = __expf(fminf(e0, 80.f));
        float w1 = __expf(fminf(e1, 80.f));
        float w2 = __expf(fminf(e2, 80.f));
        float w3 = __expf(fminf(e3, 80.f));
        w1 = j + 1 < end ? w1 : 0.f;
        w2 = j + 2 < end ? w2 : 0.f;
        w3 = j + 3 < end ? w3 : 0.f;
        denom += (w0 + w1) + (w2 + w3);
        a0 += w0 * bf2f(h0.x) + w1 * bf2f(h1.x) + w2 * bf2f(h2.x) + w3 * bf2f(h3.x);
        a1 += w0 * bf2f(h0.y) + w1 * bf2f(h1.y) + w2 * bf2f(h2.y) + w3 * bf2f(h3.y);
        a2 += w0 * bf2f(h0.z) + w1 * bf2f(h1.z) + w2 * bf2f(h2.z) + w3 * bf2f(h3.z);
        a3 += w0 * bf2f(h0.w) + w1 * bf2f(h1.w) + w2 * bf2f(h2.w) + w3 * bf2f(h3.w);
    }

    if (n0 < N) {
        float inv = 1.0f / denom;
        const float4 bv = *(const float4*)(bias + coff);
        float o0 = a0 * inv + bv.x;
        float o1 = a1 * inv + bv.y;
        float o2 = a2 * inv + bv.z;
        float o3 = a3 * inv + bv.w;
        o0 = o0 > 0.f ? o0 : (__expf(o0) - 1.f);
        o1 = o1 > 0.f ? o1 : (__expf(o1) - 1.f);
        o2 = o2 > 0.f ? o2 : (__expf(o2) - 1.f);
        o3 = o3 > 0.f ? o3 : (__expf(o3) - 1.f);
        ushort4 pk;
        pk.x = bf16r(o0); pk.y = bf16r(o1); pk.z = bf16r(o2); pk.w = bf16r(o3);
        *(ushort4*)(out16 + (size_t)n0 * HC + coff) = pk;
    }
}

// ---------------- final aggregate (H=1): r13 4-wide + log_softmax (proven) ----------------

__global__ void k_aggf_fin(const unsigned short* __restrict__ h, const float* __restrict__ s,
                           const float* __restrict__ dsc, const int* __restrict__ offs,
                           const int* __restrict__ adj, const float* __restrict__ bias,
                           float* __restrict__ out32, int N) {
    const int H = 1, C8 = 4, HC = 32;
    long tid = (long)blockIdx.x * blockDim.x + threadIdx.x;
    if (tid >= (long)N * C8) return;
    int c8 = (int)(tid % C8);
    int n  = (int)(tid / C8);
    int beg = offs[n], end = offs[n + 1];
    float dn = dsc[n * H];
    int coff = c8 * 8;
    const unsigned short* hb = h + coff;

    float denom = 0.f;
    float acc[8];
#pragma unroll
    for (int u = 0; u < 8; ++u) acc[u] = 0.f;

    for (int j = beg; j < end; j += 4) {
        int my = j + c8;
        int idx = my < end ? my : end - 1;
        int sn = adj[idx];
        float e = s[sn * H] + dn;
        e = e > 0.f ? e : LRELU_SLOPE * e;
        float w = __expf(fminf(e, 80.f));
        if (my >= end) w = 0.f;
        int wi = __builtin_bit_cast(int, w);
        int sn0 = QB(sn, 0);
        int sn1 = QB(sn, 1);
        int sn2 = QB(sn, 2);
        int sn3 = QB(sn, 3);
        float w0 = __builtin_bit_cast(float, QB(wi, 0));
        float w1 = __builtin_bit_cast(float, QB(wi, 1));
        float w2 = __builtin_bit_cast(float, QB(wi, 2));
        float w3 = __builtin_bit_cast(float, QB(wi, 3));
        short8 h0 = *(const short8*)(hb + (size_t)sn0 * HC);
        short8 h1 = *(const short8*)(hb + (size_t)sn1 * HC);
        short8 h2 = *(const short8*)(hb + (size_t)sn2 * HC);
        short8 h3 = *(const short8*)(hb + (size_t)sn3 * HC);
        denom += (w0 + w1) + (w2 + w3);
#pragma unroll
        for (int u = 0; u < 8; ++u) {
            float a01 = w0 * bf2f((unsigned short)h0[u]) + w1 * bf2f((unsigned short)h1[u]);
            float a23 = w2 * bf2f((unsigned short)h2[u]) + w3 * bf2f((unsigned short)h3[u]);
            acc[u] += a01 + a23;
        }
    }

    float inv = 1.0f / denom;
    float o[8];
#pragma unroll
    for (int u = 0; u < 8; ++u) o[u] = acc[u] * inv + bias[coff + u];

    float m = o[0];
#pragma unroll
    for (int u = 1; u < 8; ++u) m = fmaxf(m, o[u]);
    m = fmaxf(m, __shfl_xor(m, 1));
    m = fmaxf(m, __shfl_xor(m, 2));
    float ssum = 0.f;
#pragma unroll
    for (int u = 0; u < 8; ++u) ssum += __expf(o[u] - m);
    ssum += __shfl_xor(ssum, 1);
    ssum += __shfl_xor(ssum, 2);
    float lse = m + __logf(ssum);
    float4 lo = {o[0] - lse, o[1] - lse, o[2] - lse, o[3] - lse};
    float4 hi = {o[4] - lse, o[5] - lse, o[6] - lse, o[7] - lse};
    *(float4*)(out32 + tid * 8)     = lo;
    *(float4*)(out32 + tid * 8 + 4) = hi;
}

// ---------------- host ----------------

static inline size_t align_up(size_t x) { return (x + 255) & ~(size_t)255; }

extern "C" void kernel_launch(void* const* d_in, const int* in_sizes, int n_in,
                              void* d_out, int out_size, void* d_ws, size_t ws_size,
                              hipStream_t stream) {
    const float* x   = (const float*)d_in[0];
    const int*   ei  = (const int*)d_in[1];

    const int N = in_sizes[0] / 256;   // 50000
    const int E = in_sizes[1] / 2;     // 400000
    const int ET = E + N;
    const int NB = (N + 1023) / 1024;
    const int XC = N * 32;

    size_t off = 0;
    char* ws = (char*)d_ws;
    auto take = [&](size_t bytes) { char* p = ws + off; off += align_up(bytes); return p; };
    int*   cntd  = (int*)take((size_t)(N + 1) * 4);   // cnt[N] + done flag (one memset)
    int*   offs  = (int*)take((size_t)(N + 1) * 4);
    int*   offsR = (int*)take((size_t)(N + 1) * 4);
    int*   slot  = (int*)take((size_t)E * 4);
    int*   adj   = (int*)take((size_t)ET * 4);
    int*   bsum  = (int*)take((size_t)(NB + 1) * 4);
    int*   bpre  = (int*)take((size_t)(NB + 1) * 4);
    float* s0    = (float*)take((size_t)N * 8 * 4);
    float* d0    = (float*)take((size_t)N * 8 * 4);
    float* s1    = (float*)take((size_t)N * 8 * 4);
    float* d1    = (float*)take((size_t)N * 8 * 4);
    unsigned short* Xb = (unsigned short*)take((size_t)N * 256 * 2);
    unsigned short* Ya = (unsigned short*)take((size_t)N * 256 * 2);  // GEMM outs
    unsigned short* Yb = (unsigned short*)take((size_t)N * 256 * 2);  // agg outs
    unsigned short* WT0 = (unsigned short*)take((size_t)256 * 256 * 2);
    unsigned short* WT1 = (unsigned short*)take((size_t)256 * 128 * 2);
    unsigned short* WT2 = (unsigned short*)take((size_t)128 * 64 * 2);
    unsigned short* WT3 = (unsigned short*)take((size_t)64 * 32 * 2);
    (void)ws_size;

    int* cnt  = cntd;
    int* done = cntd + N;

    const float* as_[4] = {(const float*)d_in[3], (const float*)d_in[7],
                           (const float*)d_in[11], (const float*)d_in[15]};
    const float* ad_[4] = {(const float*)d_in[4], (const float*)d_in[8],
                           (const float*)d_in[12], (const float*)d_in[16]};
    const float* b_[4]  = {(const float*)d_in[5], (const float*)d_in[9],
                           (const float*)d_in[13], (const float*)d_in[17]};

    const int RB  = (N + 63) / 64;         // 782
    const int RBp = ((RB + 7) / 8) * 8;    // 784

    // 1. zero cnt+done
    hipMemsetAsync(cntd, 0, (size_t)(N + 1) * 4, stream);
    // 2. preamble
    {
        long tot = (long)XC + WTOT + E;
        k_pre<<<(int)((tot + 255) / 256), 256, 0, stream>>>(
            x, Xb,
            (const float*)d_in[2], (const float*)d_in[6], (const float*)d_in[10],
            (const float*)d_in[14], WT0, WT1, WT2, WT3, ei, cnt, slot, XC, E);
    }
    // 3. scan
    k_scan_blk<<<NB, 1024, 0, stream>>>(cnt, offsR, bsum, bpre, done, N, NB);
    // 4. finalize/scatter + GEMM L0 (fused)
    k_mg0fin<<<4 * RBp, 256, 0, stream>>>(
        ei, offsR, bpre, slot, offs, adj, NB, E,
        Xb, WT0, Ya, as_[0], ad_[0], s0, d0, N, RB);
    // 5. agg L0 (wave-per-node)
    k_aggw<8><<<(N + 3) / 4, 256, 0, stream>>>(Ya, s0, d0, offs, adj, b_[0], Yb, N);
    // 6. GEMM L1
    k_mgemm<64, 256, 2><<<2 * RBp, 256, 0, stream>>>(
        Yb, WT1, Ya, as_[1], ad_[1], s1, d1, N, 128, 4, RB);
    // 7. agg L1
    k_aggw<4><<<(N + 7) / 8, 256, 0, stream>>>(Ya, s1, d1, offs, adj, b_[1], Yb, N);
    // 8. GEMM L2
    k_mgemm<64, 128, 1><<<RBp, 256, 0, stream>>>(
        Yb, WT2, Ya, as_[2], ad_[2], s0, d0, N, 64, 2, RB);
    // 9. agg L2
    k_aggw<2><<<(N + 15) / 16, 256, 0, stream>>>(Ya, s0, d0, offs, adj, b_[2], Yb, N);
    // 10. GEMM L3
    k_mgemm<32, 64, 1><<<RBp, 256, 0, stream>>>(
        Yb, WT3, Ya, as_[3], ad_[3], s1, d1, N, 32, 1, RB);
    // 11. final aggregate + log_softmax
    k_aggf_fin<<<(int)(((long)N * 4 + 255) / 256), 256, 0, stream>>>(
        Ya, s1, d1, offs, adj, b_[3], (float*)d_out, N);
}